// Round 14
// baseline (527.769 us; speedup 1.0000x reference)
//
#include <hip/hip_runtime.h>
#include <stdint.h>

#define THETA 10.0

// ---- recurrence constants (exact truncated-kernel equivalents) ------------
struct RC {
    double trs, r2s, g1, c100, c101;   // srm: trunc at k<=99
    double trr, r2r, a1c, a33, a34;    // refractory: trunc at k<=32
};
__device__ __forceinline__ RC make_rc() {
    RC c;
    double rs = exp(-0.1); c.trs = 2.0 * rs; c.r2s = rs * rs;
    c.g1 = 0.1 * exp(0.9); c.c100 = -10.0 * exp(-9.0); c.c101 = 9.9 * exp(-9.1);
    double rr = exp(-1.0); c.trr = 2.0 * rr; c.r2r = rr * rr;
    c.a1c = -20.0; c.a33 = 660.0 * exp(-32.0); c.a34 = -640.0 * exp(-33.0);
    return c;
}
__device__ __forceinline__ int rstep(const RC& c, double din, double ta, double tb,
                                     double& y1, double& y2, double& R1, double& R2,
                                     uint64_t& mask) {
    double y = c.trs * y1 - c.r2s * y2 + c.g1 * din + c.c100 * ta + c.c101 * tb;
    y2 = y1; y1 = y;
    double R = c.trr * R1 - c.r2r * R2 + c.a1c * (double)(mask & 1ull)
             + c.a33 * (double)((mask >> 32) & 1ull)
             + c.a34 * (double)((mask >> 33) & 1ull);
    R2 = R1; R1 = R;
    int s = (y + R >= THETA) ? 1 : 0;
    mask = (mask << 1) | (uint64_t)s;
    return s;
}

// ---------------------------------------------------------------------------
// PREP (unchanged, R11-proven)
__global__ __launch_bounds__(256) void k_prep(const float* __restrict__ x,
                                              const float* __restrict__ w_fc1,
                                              const float* __restrict__ w_loc1,
                                              uint64_t* __restrict__ xb,
                                              uint64_t* __restrict__ xbT,
                                              float* __restrict__ w1t,
                                              float* __restrict__ wl1t) {
    __shared__ float shf[156 * 65];
    int b = blockIdx.x, tid = threadIdx.x;
    if (b < 512) {
        int n = b >> 3, wd = b & 7;
        int t0 = wd * 64;
        for (int e = tid; e < 156 * 64; e += 256) {
            int c = e >> 6, tt = e & 63;
            int t = t0 + tt;
            shf[c * 65 + tt] = (t < 500) ? x[(size_t)n * 78000 + (size_t)c * 500 + t] : 0.0f;
        }
        __syncthreads();
        int wv = tid >> 6, lane = tid & 63;
        for (int c = wv; c < 156; c += 4) {
            uint64_t bal = __ballot(shf[c * 65 + lane] != 0.0f);
            if (lane == 0) xbT[((size_t)n * 156 + c) * 8 + wd] = bal;
        }
        if (tid < 64) {
            int t = t0 + tid;
            if (t < 500) {
                uint64_t w0 = 0, w1 = 0, w2 = 0;
#pragma unroll
                for (int c = 0; c < 156; ++c) {
                    uint64_t bit = (shf[c * 65 + tid] != 0.0f) ? 1ull : 0ull;
                    if (c < 64) w0 |= bit << c;
                    else if (c < 128) w1 |= bit << (c - 64);
                    else w2 |= bit << (c - 128);
                }
                size_t o = ((size_t)n * 500 + t) * 4;
                xb[o] = w0; xb[o + 1] = w1; xb[o + 2] = w2; xb[o + 3] = 0;
            }
        }
    } else {
        const float* src; float* dst; int C, k0, h0;
        if (b < 536) { int tk = b - 512; src = w_fc1; dst = w1t; C = 156;
                       k0 = (tk >> 3) * 64; h0 = (tk & 7) * 64; }
        else         { int tk = b - 536; src = w_loc1; dst = wl1t; C = 500;
                       k0 = (tk >> 3) * 64; h0 = (tk & 7) * 64; }
#pragma unroll
        for (int p = 0; p < 16; ++p) {
            int e = tid + p * 256;
            int hh = e >> 6, kk = e & 63;
            int k = k0 + kk;
            shf[hh * 65 + kk] = (k < C) ? src[(size_t)(h0 + hh) * C + k] : 0.0f;
        }
        __syncthreads();
#pragma unroll
        for (int p = 0; p < 16; ++p) {
            int e = tid + p * 256;
            int hh = e & 63, kk = e >> 6;
            int k = k0 + kk;
            if (k < C) dst[(size_t)k * 512 + h0 + hh] = shf[hh * 65 + kk];
        }
    }
}

// ---------------------------------------------------------------------------
// A1 body: 5 t-steps per thread, 15 mask words, branchless interleaved gather
// (15 independent loads in flight per round; one uniform branch per round).
__device__ __forceinline__ void sdenseA5_body(const uint64_t* __restrict__ xb,
                                              const float* __restrict__ w1t,
                                              double* __restrict__ d1w,
                                              int w, int g, int n, int h) {
    int tl0 = g * 5;
    const uint64_t* mb = xb + ((size_t)n * 500 + w * 125 + tl0) * 4;
    uint64_t m[15];
#pragma unroll
    for (int i = 0; i < 5; ++i) {
        m[i * 3 + 0] = mb[i * 4 + 0];
        m[i * 3 + 1] = mb[i * 4 + 1];
        m[i * 3 + 2] = mb[i * 4 + 2];
    }
    double d[5];
#pragma unroll
    for (int i = 0; i < 5; ++i) d[i] = 0.0;
    while (true) {
        uint64_t any = 0;
#pragma unroll
        for (int q = 0; q < 15; ++q) any |= m[q];
        if (!any) break;
        double v[15];
#pragma unroll
        for (int q = 0; q < 15; ++q) {
            int wd = q % 3;
            uint64_t sent = (wd == 2) ? (1ull << 27) : 0x8000000000000000ull;
            int bb = (int)__builtin_ctzll(m[q] | sent);
            v[q] = (double)w1t[(size_t)(wd * 64 + bb) * 512 + h];
        }
#pragma unroll
        for (int q = 0; q < 15; ++q) {
            d[q / 3] += (m[q] != 0) ? v[q] : 0.0;
            m[q] &= m[q] - 1;
        }
    }
#pragma unroll
    for (int i = 0; i < 5; ++i)
        d1w[(size_t)(tl0 + i) * 32768 + n * 512 + h] = d[i];
}

// B1 body: 2 taxels per thread, 16 mask words, same branchless structure.
__device__ __forceinline__ void sdenseB2_body(const uint64_t* __restrict__ xbT,
                                              const float* __restrict__ wl1t,
                                              double* __restrict__ e,
                                              int g, int n, int h) {
    int c0 = g * 2;
    const uint64_t* mb = xbT + ((size_t)n * 156 + c0) * 8;
    uint64_t m[16];
#pragma unroll
    for (int q = 0; q < 16; ++q) m[q] = mb[q];
    double d[2];
    d[0] = 0.0; d[1] = 0.0;
    while (true) {
        uint64_t any = 0;
#pragma unroll
        for (int q = 0; q < 16; ++q) any |= m[q];
        if (!any) break;
        double v[16];
#pragma unroll
        for (int q = 0; q < 16; ++q) {
            int wd = q & 7;
            uint64_t sent = (wd == 7) ? (1ull << 51) : 0x8000000000000000ull;
            int bb = (int)__builtin_ctzll(m[q] | sent);
            v[q] = (double)wl1t[(size_t)(wd * 64 + bb) * 512 + h];
        }
#pragma unroll
        for (int q = 0; q < 16; ++q) {
            d[q >> 3] += (m[q] != 0) ? v[q] : 0.0;
            m[q] &= m[q] - 1;
        }
    }
    e[((size_t)n * 156 + c0) * 512 + h] = d[0];
    e[((size_t)n * 156 + c0 + 1) * 512 + h] = d[1];
}

// A1 windows 1..3: grid (25, 64, 2) x 256
__global__ __launch_bounds__(256) void k_sdenseA(const uint64_t* __restrict__ xb,
                                                 const float* __restrict__ w1t,
                                                 double* __restrict__ d1w, int w) {
    sdenseA5_body(xb, w1t, d1w, w, blockIdx.x, blockIdx.y,
                  blockIdx.z * 256 + threadIdx.x);
}

// Merged sdenseA(w0) + sdenseB: 13184 blocks x 256
__global__ __launch_bounds__(256) void k_sdense0(const uint64_t* __restrict__ xb,
                                                 const float* __restrict__ w1t,
                                                 double* __restrict__ d1w,
                                                 const uint64_t* __restrict__ xbT,
                                                 const float* __restrict__ wl1t,
                                                 double* __restrict__ e) {
    int b = blockIdx.x, tid = threadIdx.x;
    if (b < 3200) {
        int g = b % 25, r = b / 25;
        sdenseA5_body(xb, w1t, d1w, 0, g, r & 63, (r >> 6) * 256 + tid);
    } else {
        int idx = b - 3200;
        int g = idx % 78, r = idx / 78;
        sdenseB2_body(xbT, wl1t, e, g, r & 63, (r >> 6) * 256 + tid);
    }
}

// ---------------------------------------------------------------------------
// rscanA body: ring pattern, 24-deep register prefetch (5 chunks x 24 + 5).
__device__ __forceinline__ void rscanA_body(const double* __restrict__ cur,
                                            const double* __restrict__ prev,
                                            uint64_t* __restrict__ s1w,
                                            double* stY1, double* stY2,
                                            double* stR1, double* stR2,
                                            double* stDp, uint64_t* stM,
                                            int w, int lane, int blk,
                                            double (*ring)[64]) {
    int gid = blk * 64 + lane;                  // n*512 + h
    int n = gid >> 9, word = (gid >> 6) & 7;
    RC rc = make_rc();
    int t0g = w * 125;
    double y1, y2, R1, R2, dp; uint64_t mask;
    if (w == 0) { y1 = y2 = R1 = R2 = dp = 0.0; mask = 0; }
    else {
        y1 = stY1[gid]; y2 = stY2[gid]; R1 = stR1[gid]; R2 = stR2[gid];
        dp = stDp[gid]; mask = stM[gid];
#pragma unroll 4
        for (int k = 0; k < 101; ++k)
            ring[(t0g - 101 + k) & 127][lane] = prev[(size_t)(24 + k) * 32768 + gid];
    }
    double curv[24], nxt[24];
#pragma unroll
    for (int i = 0; i < 24; ++i) curv[i] = cur[(size_t)i * 32768 + gid];
    for (int ch = 0; ch < 5; ++ch) {
        int b0 = ch * 24;
#pragma unroll
        for (int i = 0; i < 24; ++i) {
            int l = b0 + 24 + i;
            nxt[i] = (l < 125) ? cur[(size_t)l * 32768 + gid] : 0.0;
        }
#pragma unroll
        for (int i = 0; i < 24; ++i) ring[(t0g + b0 + i) & 127][lane] = curv[i];
#pragma unroll
        for (int i = 0; i < 24; ++i) {
            int tg = t0g + b0 + i;
            double ta = (tg >= 100) ? ring[(tg - 100) & 127][lane] : 0.0;
            double tb = (tg >= 101) ? ring[(tg - 101) & 127][lane] : 0.0;
            int s = rstep(rc, (i == 0) ? dp : curv[i - 1], ta, tb, y1, y2, R1, R2, mask);
            uint64_t bal = __ballot(s != 0);
            if (lane == 0) s1w[((size_t)n * 500 + tg) * 8 + word] = bal;
        }
        dp = curv[23];
#pragma unroll
        for (int i = 0; i < 24; ++i) curv[i] = nxt[i];
    }
    // tail: local t 120..124 in curv[0..4]; tg >= 120 so taps always valid
#pragma unroll
    for (int i = 0; i < 5; ++i) ring[(t0g + 120 + i) & 127][lane] = curv[i];
#pragma unroll
    for (int i = 0; i < 5; ++i) {
        int tg = t0g + 120 + i;
        double ta = ring[(tg - 100) & 127][lane];
        double tb = ring[(tg - 101) & 127][lane];
        int s = rstep(rc, (i == 0) ? dp : curv[i - 1], ta, tb, y1, y2, R1, R2, mask);
        uint64_t bal = __ballot(s != 0);
        if (lane == 0) s1w[((size_t)n * 500 + tg) * 8 + word] = bal;
    }
    dp = curv[4];
    stY1[gid] = y1; stY2[gid] = y2; stR1[gid] = R1; stR2[gid] = R2;
    stDp[gid] = dp; stM[gid] = mask;
}

// rscanB body: 24-deep (6 chunks x 24 + tail 12).
__device__ __forceinline__ void rscanB_body(const double* __restrict__ e,
                                            const int* pl,
                                            uint64_t* __restrict__ s1bw,
                                            int lane, int blk,
                                            double (*ring)[64]) {
    int gid = blk * 64 + lane;                  // n*512 + h
    int n = gid >> 9, h = gid & 511, word = (gid >> 6) & 7;
    const double* en = e + (size_t)n * 156 * 512;
    RC rc = make_rc();
    double y1 = 0.0, y2 = 0.0, R1 = 0.0, R2 = 0.0, dp = 0.0; uint64_t mask = 0;
    double curv[24], nxt[24];
#pragma unroll
    for (int i = 0; i < 24; ++i) curv[i] = en[(size_t)pl[i] * 512 + h];
    for (int ch = 0; ch < 6; ++ch) {
        int b0 = ch * 24;
#pragma unroll
        for (int i = 0; i < 24; ++i) {
            int l = b0 + 24 + i;
            int ll = (l < 156) ? l : 0;
            nxt[i] = (l < 156) ? en[(size_t)pl[ll] * 512 + h] : 0.0;
        }
#pragma unroll
        for (int i = 0; i < 24; ++i) ring[(b0 + i) & 127][lane] = curv[i];
#pragma unroll
        for (int i = 0; i < 24; ++i) {
            int j = b0 + i;
            double ta = (j >= 100) ? ring[(j - 100) & 127][lane] : 0.0;
            double tb = (j >= 101) ? ring[(j - 101) & 127][lane] : 0.0;
            int s = rstep(rc, (i == 0) ? dp : curv[i - 1], ta, tb, y1, y2, R1, R2, mask);
            uint64_t bal = __ballot(s != 0);
            if (lane == 0) s1bw[((size_t)n * 156 + j) * 8 + word] = bal;
        }
        dp = curv[23];
#pragma unroll
        for (int i = 0; i < 24; ++i) curv[i] = nxt[i];
    }
    // tail: j 144..155 in curv[0..11]
#pragma unroll
    for (int i = 0; i < 12; ++i) ring[(144 + i) & 127][lane] = curv[i];
#pragma unroll
    for (int i = 0; i < 12; ++i) {
        int j = 144 + i;
        double ta = ring[(j - 100) & 127][lane];
        double tb = ring[(j - 101) & 127][lane];
        int s = rstep(rc, (i == 0) ? dp : curv[i - 1], ta, tb, y1, y2, R1, R2, mask);
        uint64_t bal = __ballot(s != 0);
        if (lane == 0) s1bw[((size_t)n * 156 + j) * 8 + word] = bal;
    }
}

// rscanA windows 1..3 (512 blocks x 64)
__global__ __launch_bounds__(64) void k_rscanA(const double* __restrict__ cur,
                                               const double* __restrict__ prev,
                                               uint64_t* __restrict__ s1w,
                                               double* stY1, double* stY2,
                                               double* stR1, double* stR2,
                                               double* stDp, uint64_t* stM, int w) {
    __shared__ double ring[128][64];
    rscanA_body(cur, prev, s1w, stY1, stY2, stR1, stR2, stDp, stM,
                w, threadIdx.x, blockIdx.x, ring);
}

// Merged rscanA(w0) + rscanB: 1024 blocks x 64
__global__ __launch_bounds__(64) void k_rscan0(const double* __restrict__ cur,
                                               uint64_t* __restrict__ s1w,
                                               double* stY1, double* stY2,
                                               double* stR1, double* stR2,
                                               double* stDp, uint64_t* stM,
                                               const double* __restrict__ e,
                                               const int* __restrict__ perm,
                                               uint64_t* __restrict__ s1bw) {
    __shared__ double ring[128][64];
    __shared__ int pl[156];
    int b = blockIdx.x, lane = threadIdx.x;
    if (b < 512) {
        rscanA_body(cur, cur, s1w, stY1, stY2, stR1, stR2, stDp, stM,
                    0, lane, b, ring);
    } else {
        for (int i = lane; i < 156; i += 64) pl[i] = perm[i];
        __syncthreads();
        rscanB_body(e, pl, s1bw, lane, b - 512, ring);
    }
}

// ---------------------------------------------------------------------------
// DENSE2 (merged A+B): a2[t][1280], a2b[j][1280], col = n*20+o. (unchanged)
__global__ __launch_bounds__(256) void k_dense2m(const uint64_t* __restrict__ s1w,
                                                 const uint64_t* __restrict__ s1bw,
                                                 const float* __restrict__ w_fc2,
                                                 const float* __restrict__ w_loc2,
                                                 double* __restrict__ a2,
                                                 double* __restrict__ a2b) {
    __shared__ float wt[512 * 20];
    int b = blockIdx.x, tid = threadIdx.x;
    int isA = (b < 125);
    const float* w = isA ? w_fc2 : w_loc2;
    const uint64_t* sw = isA ? s1w : s1bw;
    double* a = isA ? a2 : a2b;
    int T = isA ? 500 : 156;
    int gid = (isA ? b : (b - 125)) * 256 + tid;
    for (int e = tid; e < 512 * 20; e += 256) { int o = e / 512, hh = e % 512; wt[hh * 20 + o] = w[e]; }
    __syncthreads();
    if (gid >= 64 * T) return;
    int n = gid / T, t = gid - n * T;
    const uint64_t* r = sw + ((size_t)n * T + t) * 8;
    uint64_t wbuf[8];
#pragma unroll
    for (int wd = 0; wd < 8; ++wd) wbuf[wd] = r[wd];
    double acc[20];
#pragma unroll
    for (int o = 0; o < 20; ++o) acc[o] = 0.0;
#pragma unroll
    for (int wd = 0; wd < 8; ++wd) {
        uint64_t mw = wbuf[wd];
        while (mw) {
            int bb = __builtin_ctzll(mw);
            const float* wp = wt + (wd * 64 + bb) * 20;
#pragma unroll
            for (int o = 0; o < 20; ++o) acc[o] += (double)wp[o];
            mw &= mw - 1;
        }
    }
#pragma unroll
    for (int o = 0; o < 20; ++o) a[(size_t)t * 1280 + n * 20 + o] = acc[o];
}

// ---------------------------------------------------------------------------
// OUT (k_out3): 24-step chunks (unchanged from R13).
template<int NFULL, int TAIL>
__device__ __forceinline__ void ring_scan(const double* __restrict__ a, int row,
                                          double (*ring)[64],
                                          uint32_t (*bits)[64], int lane) {
    RC rc = make_rc();
    double y1 = 0.0, y2 = 0.0, R1 = 0.0, R2 = 0.0, dp = 0.0; uint64_t mask = 0;
    double cur[24], nxt[24];
#pragma unroll
    for (int i = 0; i < 24; ++i) cur[i] = a[(size_t)i * 1280 + row];
    for (int ch = 0; ch < NFULL; ++ch) {
        int t0 = ch * 24;
        if (ch + 1 < NFULL) {
#pragma unroll
            for (int i = 0; i < 24; ++i) nxt[i] = a[(size_t)(t0 + 24 + i) * 1280 + row];
        } else if (TAIL > 0) {
#pragma unroll
            for (int i = 0; i < 24; ++i)
                nxt[i] = (i < TAIL) ? a[(size_t)(t0 + 24 + i) * 1280 + row] : 0.0;
        }
#pragma unroll
        for (int i = 0; i < 24; ++i) ring[(t0 + i) & 127][lane] = cur[i];
        double tap[25];
#pragma unroll
        for (int i = 0; i < 25; ++i) {
            int l = t0 + i - 101;
            tap[i] = (l >= 0) ? ring[l & 127][lane] : 0.0;
        }
        uint32_t sp = 0;
#pragma unroll
        for (int i = 0; i < 24; ++i) {
            int s = rstep(rc, (i == 0) ? dp : cur[i - 1], tap[i + 1], tap[i],
                          y1, y2, R1, R2, mask);
            sp |= (uint32_t)s << i;
        }
        dp = cur[23];
        bits[ch][lane] = sp;
#pragma unroll
        for (int i = 0; i < 24; ++i) cur[i] = nxt[i];
    }
    if (TAIL > 0) {
        int t0 = NFULL * 24;
#pragma unroll
        for (int i = 0; i < 24; ++i) if (i < TAIL) ring[(t0 + i) & 127][lane] = cur[i];
        double tap[25];
#pragma unroll
        for (int i = 0; i < 25; ++i) {
            if (i > TAIL) break;
            int l = t0 + i - 101;
            tap[i] = (l >= 0) ? ring[l & 127][lane] : 0.0;
        }
        uint32_t sp = 0;
#pragma unroll
        for (int i = 0; i < 24; ++i) {
            if (i >= TAIL) break;
            int s = rstep(rc, (i == 0) ? dp : cur[i - 1], tap[i + 1], tap[i],
                          y1, y2, R1, R2, mask);
            sp |= (uint32_t)s << i;
        }
        bits[NFULL][lane] = sp;
    }
}

template<int T>
__device__ __forceinline__ void expand_bits(uint32_t (*bits)[64],
                                            float* __restrict__ out,
                                            int row0, int coff, int lane) {
    for (int r = 0; r < 64; ++r) {
        float* orow = out + (size_t)(row0 + r) * 656 + coff;
        for (int c0 = 0; c0 < T; c0 += 64) {
            int c = c0 + lane;
            if (c < T) orow[c] = (float)((bits[c / 24][r] >> (c % 24)) & 1);
        }
    }
}

__global__ __launch_bounds__(64) void k_out3(const double* __restrict__ a2,
                                             const double* __restrict__ a2b,
                                             float* __restrict__ out) {
    __shared__ double ring[128][64];
    __shared__ uint32_t bits[21][64];
    int b = blockIdx.x, lane = threadIdx.x;
    if (b < 20) {
        int row0 = b * 64;
        ring_scan<20, 20>(a2, row0 + lane, ring, bits, lane);   // 500 = 20*24+20
        expand_bits<500>(bits, out, row0, 0, lane);
    } else {
        int row0 = (b - 20) * 64;
        ring_scan<6, 12>(a2b, row0 + lane, ring, bits, lane);   // 156 = 6*24+12
        expand_bits<156>(bits, out, row0, 500, lane);
    }
}

// ---------------------------------------------------------------------------
extern "C" void kernel_launch(void* const* d_in, const int* in_sizes, int n_in,
                              void* d_out, int out_size, void* d_ws, size_t ws_size,
                              hipStream_t stream) {
    const float* x      = (const float*)d_in[0];
    const float* w_fc1  = (const float*)d_in[1];
    const float* w_fc2  = (const float*)d_in[2];
    const float* w_loc1 = (const float*)d_in[3];
    const float* w_loc2 = (const float*)d_in[4];
    const int*   perm   = (const int*)d_in[5];
    float* out = (float*)d_out;
    char* ws = (char*)d_ws;
    (void)ws_size; (void)in_sizes; (void)n_in; (void)out_size;

    // R13-proven layout (ws_size >= 114,208,768 confirmed by R13 main path).
    double*   d1b0 = (double*)(ws + 0);             // 32,768,000 B
    double*   d1b1 = (double*)(ws + 32768000);      // 32,768,000 B
    double*   a2   = (double*)(ws + 40894464);      //  5,120,000 B (overlays d1b1; dead by then)
    double*   a2b  = (double*)(ws + 46014464);      //  1,597,440 B (overlays d1b1)
    double*   e    = (double*)(ws + 65536000);      // 40,894,464 B [n][c][512]
    uint64_t* s1w  = (uint64_t*)(ws + 106430464);   //  2,560,000 B
    uint64_t* s1bw = (uint64_t*)(ws + 108990464);   //    638,976 B
    uint64_t* xb   = (uint64_t*)(ws + 109629440);   //  1,024,000 B
    uint64_t* xbT  = (uint64_t*)(ws + 110653440);   //    638,976 B
    float*    w1t  = (float*)(ws + 111292416);      //    319,488 B
    float*    wl1t = (float*)(ws + 111611904);      //  1,024,000 B
    double*   stY1 = (double*)(ws + 112635904);     //    262,144 B
    double*   stY2 = (double*)(ws + 112898048);     //    262,144 B
    double*   stR1 = (double*)(ws + 113160192);     //    262,144 B
    double*   stR2 = (double*)(ws + 113422336);     //    262,144 B
    double*   stDp = (double*)(ws + 113684480);     //    262,144 B
    uint64_t* stM  = (uint64_t*)(ws + 113946624);   //    262,144 B

    k_prep<<<600, 256, 0, stream>>>(x, w_fc1, w_loc1, xb, xbT, w1t, wl1t);
    // sdenseA(w0) merged with sdenseB
    k_sdense0<<<13184, 256, 0, stream>>>(xb, w1t, d1b0, xbT, wl1t, e);
    // rscanA(w0) merged with rscanB
    k_rscan0<<<1024, 64, 0, stream>>>(d1b0, s1w, stY1, stY2, stR1, stR2, stDp, stM, e, perm, s1bw);
    // windows 1..3
    dim3 ga(25, 64, 2);
    for (int w = 1; w < 4; ++w) {
        double* cur  = (w & 1) ? d1b1 : d1b0;
        double* prev = (w & 1) ? d1b0 : d1b1;
        k_sdenseA<<<ga, 256, 0, stream>>>(xb, w1t, cur, w);
        k_rscanA<<<512, 64, 0, stream>>>(cur, prev, s1w, stY1, stY2, stR1, stR2, stDp, stM, w);
    }
    // layer 2
    k_dense2m<<<164, 256, 0, stream>>>(s1w, s1bw, w_fc2, w_loc2, a2, a2b);
    k_out3<<<40, 64, 0, stream>>>(a2, a2b, out);
}

// Round 15
// 452.862 us; speedup vs baseline: 1.1654x; 1.1654x over previous
//
#include <hip/hip_runtime.h>
#include <stdint.h>

#define THETA 10.0

// ---- recurrence constants (exact truncated-kernel equivalents) ------------
struct RC {
    double trs, r2s, g1, c100, c101;   // srm: trunc at k<=99
    double trr, r2r, a1c, a33, a34;    // refractory: trunc at k<=32
};
__device__ __forceinline__ RC make_rc() {
    RC c;
    double rs = exp(-0.1); c.trs = 2.0 * rs; c.r2s = rs * rs;
    c.g1 = 0.1 * exp(0.9); c.c100 = -10.0 * exp(-9.0); c.c101 = 9.9 * exp(-9.1);
    double rr = exp(-1.0); c.trr = 2.0 * rr; c.r2r = rr * rr;
    c.a1c = -20.0; c.a33 = 660.0 * exp(-32.0); c.a34 = -640.0 * exp(-33.0);
    return c;
}
__device__ __forceinline__ int rstep(const RC& c, double din, double ta, double tb,
                                     double& y1, double& y2, double& R1, double& R2,
                                     uint64_t& mask) {
    double y = c.trs * y1 - c.r2s * y2 + c.g1 * din + c.c100 * ta + c.c101 * tb;
    y2 = y1; y1 = y;
    double R = c.trr * R1 - c.r2r * R2 + c.a1c * (double)(mask & 1ull)
             + c.a33 * (double)((mask >> 32) & 1ull)
             + c.a34 * (double)((mask >> 33) & 1ull);
    R2 = R1; R1 = R;
    int s = (y + R >= THETA) ? 1 : 0;
    mask = (mask << 1) | (uint64_t)s;
    return s;
}

// ---------------------------------------------------------------------------
// PREP (unchanged, R11-proven)
__global__ __launch_bounds__(256) void k_prep(const float* __restrict__ x,
                                              const float* __restrict__ w_fc1,
                                              const float* __restrict__ w_loc1,
                                              uint64_t* __restrict__ xb,
                                              uint64_t* __restrict__ xbT,
                                              float* __restrict__ w1t,
                                              float* __restrict__ wl1t) {
    __shared__ float shf[156 * 65];
    int b = blockIdx.x, tid = threadIdx.x;
    if (b < 512) {
        int n = b >> 3, wd = b & 7;
        int t0 = wd * 64;
        for (int e = tid; e < 156 * 64; e += 256) {
            int c = e >> 6, tt = e & 63;
            int t = t0 + tt;
            shf[c * 65 + tt] = (t < 500) ? x[(size_t)n * 78000 + (size_t)c * 500 + t] : 0.0f;
        }
        __syncthreads();
        int wv = tid >> 6, lane = tid & 63;
        for (int c = wv; c < 156; c += 4) {
            uint64_t bal = __ballot(shf[c * 65 + lane] != 0.0f);
            if (lane == 0) xbT[((size_t)n * 156 + c) * 8 + wd] = bal;
        }
        if (tid < 64) {
            int t = t0 + tid;
            if (t < 500) {
                uint64_t w0 = 0, w1 = 0, w2 = 0;
#pragma unroll
                for (int c = 0; c < 156; ++c) {
                    uint64_t bit = (shf[c * 65 + tid] != 0.0f) ? 1ull : 0ull;
                    if (c < 64) w0 |= bit << c;
                    else if (c < 128) w1 |= bit << (c - 64);
                    else w2 |= bit << (c - 128);
                }
                size_t o = ((size_t)n * 500 + t) * 4;
                xb[o] = w0; xb[o + 1] = w1; xb[o + 2] = w2; xb[o + 3] = 0;
            }
        }
    } else {
        const float* src; float* dst; int C, k0, h0;
        if (b < 536) { int tk = b - 512; src = w_fc1; dst = w1t; C = 156;
                       k0 = (tk >> 3) * 64; h0 = (tk & 7) * 64; }
        else         { int tk = b - 536; src = w_loc1; dst = wl1t; C = 500;
                       k0 = (tk >> 3) * 64; h0 = (tk & 7) * 64; }
#pragma unroll
        for (int p = 0; p < 16; ++p) {
            int e = tid + p * 256;
            int hh = e >> 6, kk = e & 63;
            int k = k0 + kk;
            shf[hh * 65 + kk] = (k < C) ? src[(size_t)(h0 + hh) * C + k] : 0.0f;
        }
        __syncthreads();
#pragma unroll
        for (int p = 0; p < 16; ++p) {
            int e = tid + p * 256;
            int hh = e & 63, kk = e >> 6;
            int k = k0 + kk;
            if (k < C) dst[(size_t)k * 512 + h0 + hh] = shf[hh * 65 + kk];
        }
    }
}

// ---------------------------------------------------------------------------
// Batch-4 per-word gather: 4 independent loads in flight per round, addresses
// mask-only (no load deps), left-fold add order identical to serial walk.
// sent = in-bounds sentinel bit for this word.
__device__ __forceinline__ void gather4(uint64_t m, const float* __restrict__ wv,
                                        int h, uint64_t sent, double& d) {
    while (m) {
        uint64_t m1 = m & (m - 1), m2 = m1 & (m1 - 1), m3 = m2 & (m2 - 1);
        int i0 = (int)__builtin_ctzll(m);
        int i1 = (int)__builtin_ctzll(m1 | sent);
        int i2 = (int)__builtin_ctzll(m2 | sent);
        int i3 = (int)__builtin_ctzll(m3 | sent);
        double v0 = (double)wv[(size_t)i0 * 512 + h];
        double v1 = (double)wv[(size_t)i1 * 512 + h];
        double v2 = (double)wv[(size_t)i2 * 512 + h];
        double v3 = (double)wv[(size_t)i3 * 512 + h];
        d += v0;
        d += (m1 != 0) ? v1 : 0.0;
        d += (m2 != 0) ? v2 : 0.0;
        d += (m3 != 0) ? v3 : 0.0;
        m = m3 & (m3 - 1);
    }
}

// A1 body: 1 t per thread, 3 words, batch-4 gather per word.
__device__ __forceinline__ void sdenseA_body(const uint64_t* __restrict__ xb,
                                             const float* __restrict__ w1t,
                                             double* __restrict__ d1w,
                                             int w, int tl, int n, int h) {
    const uint64_t* mb = xb + ((size_t)n * 500 + w * 125 + tl) * 4;
    uint64_t m0 = mb[0], m1 = mb[1], m2 = mb[2];
    double d0 = 0.0, d1 = 0.0, d2 = 0.0;
    gather4(m0, w1t, h, 0x8000000000000000ull, d0);            // bit63 -> c63 ok
    gather4(m1, w1t + (size_t)64 * 512, h, 0x8000000000000000ull, d1);  // c127 ok
    gather4(m2, w1t + (size_t)128 * 512, h, 1ull << 27, d2);   // bit27 -> c155 ok
    d1w[(size_t)tl * 32768 + n * 512 + h] = (d0 + d1) + d2;
}

// B1 body: 1 c per thread, 8 words, batch-4 gather per word (single fold).
__device__ __forceinline__ void sdenseB_body(const uint64_t* __restrict__ xbT,
                                             const float* __restrict__ wl1t,
                                             double* __restrict__ e,
                                             int c, int n, int h) {
    const uint64_t* mb = xbT + ((size_t)n * 156 + c) * 8;
    double d = 0.0;
#pragma unroll
    for (int wd = 0; wd < 8; ++wd) {
        uint64_t sent = (wd == 7) ? (1ull << 51) : 0x8000000000000000ull;
        gather4(mb[wd], wl1t + (size_t)wd * 64 * 512, h, sent, d);
    }
    e[((size_t)n * 156 + c) * 512 + h] = d;
}

// A1 (windows 1..3): grid (125,64,2) x 256
__global__ __launch_bounds__(256) void k_sdenseA(const uint64_t* __restrict__ xb,
                                                 const float* __restrict__ w1t,
                                                 double* __restrict__ d1w, int w) {
    sdenseA_body(xb, w1t, d1w, w, blockIdx.x, blockIdx.y,
                 blockIdx.z * 256 + threadIdx.x);
}

// Merged sdenseA(w0) + sdenseB: one dispatch, 35968 blocks x 256
__global__ __launch_bounds__(256) void k_sdense0(const uint64_t* __restrict__ xb,
                                                 const float* __restrict__ w1t,
                                                 double* __restrict__ d1w,
                                                 const uint64_t* __restrict__ xbT,
                                                 const float* __restrict__ wl1t,
                                                 double* __restrict__ e) {
    int b = blockIdx.x, tid = threadIdx.x;
    if (b < 16000) {
        int tl = b % 125, r = b / 125;          // r in [0,128)
        int n = r & 63, hz = r >> 6;
        sdenseA_body(xb, w1t, d1w, 0, tl, n, hz * 256 + tid);
    } else {
        int idx = b - 16000;                    // [0, 19968)
        int c = idx % 156, r = idx / 156;       // r in [0,128)
        int n = r & 63, hz = r >> 6;
        sdenseB_body(xbT, wl1t, e, c, n, hz * 256 + tid);
    }
}

// ---- rscanA body (ring pattern, 12-deep, R13-verified) ---------------------
__device__ __forceinline__ void rscanA_body(const double* __restrict__ cur,
                                            const double* __restrict__ prev,
                                            uint64_t* __restrict__ s1w,
                                            double* stY1, double* stY2,
                                            double* stR1, double* stR2,
                                            double* stDp, uint64_t* stM,
                                            int w, int lane, int blk,
                                            double (*ring)[64]) {
    int gid = blk * 64 + lane;                  // n*512 + h
    int n = gid >> 9, word = (gid >> 6) & 7;
    RC rc = make_rc();
    int t0g = w * 125;
    double y1, y2, R1, R2, dp; uint64_t mask;
    if (w == 0) { y1 = y2 = R1 = R2 = dp = 0.0; mask = 0; }
    else {
        y1 = stY1[gid]; y2 = stY2[gid]; R1 = stR1[gid]; R2 = stR2[gid];
        dp = stDp[gid]; mask = stM[gid];
#pragma unroll 4
        for (int k = 0; k < 101; ++k)
            ring[(t0g - 101 + k) & 127][lane] = prev[(size_t)(24 + k) * 32768 + gid];
    }
    double curv[12], nxt[12];
#pragma unroll
    for (int i = 0; i < 12; ++i) curv[i] = cur[(size_t)i * 32768 + gid];
    for (int ch = 0; ch < 10; ++ch) {
        int b0 = ch * 12;
#pragma unroll
        for (int i = 0; i < 12; ++i) {
            int l = b0 + 12 + i;
            nxt[i] = (l < 125) ? cur[(size_t)l * 32768 + gid] : 0.0;
        }
#pragma unroll
        for (int i = 0; i < 12; ++i) ring[(t0g + b0 + i) & 127][lane] = curv[i];
#pragma unroll
        for (int i = 0; i < 12; ++i) {
            int tg = t0g + b0 + i;
            double ta = (tg >= 100) ? ring[(tg - 100) & 127][lane] : 0.0;
            double tb = (tg >= 101) ? ring[(tg - 101) & 127][lane] : 0.0;
            int s = rstep(rc, (i == 0) ? dp : curv[i - 1], ta, tb, y1, y2, R1, R2, mask);
            uint64_t bal = __ballot(s != 0);
            if (lane == 0) s1w[((size_t)n * 500 + tg) * 8 + word] = bal;
        }
        dp = curv[11];
#pragma unroll
        for (int i = 0; i < 12; ++i) curv[i] = nxt[i];
    }
#pragma unroll
    for (int i = 0; i < 5; ++i) ring[(t0g + 120 + i) & 127][lane] = curv[i];
#pragma unroll
    for (int i = 0; i < 5; ++i) {
        int tg = t0g + 120 + i;
        double ta = ring[(tg - 100) & 127][lane];
        double tb = ring[(tg - 101) & 127][lane];
        int s = rstep(rc, (i == 0) ? dp : curv[i - 1], ta, tb, y1, y2, R1, R2, mask);
        uint64_t bal = __ballot(s != 0);
        if (lane == 0) s1w[((size_t)n * 500 + tg) * 8 + word] = bal;
    }
    dp = curv[4];
    stY1[gid] = y1; stY2[gid] = y2; stR1[gid] = R1; stR2[gid] = R2;
    stDp[gid] = dp; stM[gid] = mask;
}

__device__ __forceinline__ void rscanB_body(const double* __restrict__ e,
                                            const int* pl,
                                            uint64_t* __restrict__ s1bw,
                                            int lane, int blk,
                                            double (*ring)[64]) {
    int gid = blk * 64 + lane;                  // n*512 + h
    int n = gid >> 9, h = gid & 511, word = (gid >> 6) & 7;
    const double* en = e + (size_t)n * 156 * 512;
    RC rc = make_rc();
    double y1 = 0.0, y2 = 0.0, R1 = 0.0, R2 = 0.0, dp = 0.0; uint64_t mask = 0;
    double curv[12], nxt[12];
#pragma unroll
    for (int i = 0; i < 12; ++i) curv[i] = en[(size_t)pl[i] * 512 + h];
    for (int ch = 0; ch < 13; ++ch) {
        int b0 = ch * 12;
        if (ch < 12) {
#pragma unroll
            for (int i = 0; i < 12; ++i) nxt[i] = en[(size_t)pl[b0 + 12 + i] * 512 + h];
        }
#pragma unroll
        for (int i = 0; i < 12; ++i) ring[(b0 + i) & 127][lane] = curv[i];
#pragma unroll
        for (int i = 0; i < 12; ++i) {
            int j = b0 + i;
            double ta = (j >= 100) ? ring[(j - 100) & 127][lane] : 0.0;
            double tb = (j >= 101) ? ring[(j - 101) & 127][lane] : 0.0;
            int s = rstep(rc, (i == 0) ? dp : curv[i - 1], ta, tb, y1, y2, R1, R2, mask);
            uint64_t bal = __ballot(s != 0);
            if (lane == 0) s1bw[((size_t)n * 156 + j) * 8 + word] = bal;
        }
        dp = curv[11];
#pragma unroll
        for (int i = 0; i < 12; ++i) curv[i] = nxt[i];
    }
}

// rscanA windows 1..3 (512 blocks x 64)
__global__ __launch_bounds__(64) void k_rscanA(const double* __restrict__ cur,
                                               const double* __restrict__ prev,
                                               uint64_t* __restrict__ s1w,
                                               double* stY1, double* stY2,
                                               double* stR1, double* stR2,
                                               double* stDp, uint64_t* stM, int w) {
    __shared__ double ring[128][64];
    rscanA_body(cur, prev, s1w, stY1, stY2, stR1, stR2, stDp, stM,
                w, threadIdx.x, blockIdx.x, ring);
}

// Merged rscanA(w0) + rscanB: 1024 blocks x 64
__global__ __launch_bounds__(64) void k_rscan0(const double* __restrict__ cur,
                                               uint64_t* __restrict__ s1w,
                                               double* stY1, double* stY2,
                                               double* stR1, double* stR2,
                                               double* stDp, uint64_t* stM,
                                               const double* __restrict__ e,
                                               const int* __restrict__ perm,
                                               uint64_t* __restrict__ s1bw) {
    __shared__ double ring[128][64];
    __shared__ int pl[156];
    int b = blockIdx.x, lane = threadIdx.x;
    if (b < 512) {
        rscanA_body(cur, cur, s1w, stY1, stY2, stR1, stR2, stDp, stM,
                    0, lane, b, ring);
    } else {
        for (int i = lane; i < 156; i += 64) pl[i] = perm[i];
        __syncthreads();
        rscanB_body(e, pl, s1bw, lane, b - 512, ring);
    }
}

// ---------------------------------------------------------------------------
// DENSE2 (merged A+B): a2[t][1280], a2b[j][1280], col = n*20+o. (unchanged)
__global__ __launch_bounds__(256) void k_dense2m(const uint64_t* __restrict__ s1w,
                                                 const uint64_t* __restrict__ s1bw,
                                                 const float* __restrict__ w_fc2,
                                                 const float* __restrict__ w_loc2,
                                                 double* __restrict__ a2,
                                                 double* __restrict__ a2b) {
    __shared__ float wt[512 * 20];
    int b = blockIdx.x, tid = threadIdx.x;
    int isA = (b < 125);
    const float* w = isA ? w_fc2 : w_loc2;
    const uint64_t* sw = isA ? s1w : s1bw;
    double* a = isA ? a2 : a2b;
    int T = isA ? 500 : 156;
    int gid = (isA ? b : (b - 125)) * 256 + tid;
    for (int e = tid; e < 512 * 20; e += 256) { int o = e / 512, hh = e % 512; wt[hh * 20 + o] = w[e]; }
    __syncthreads();
    if (gid >= 64 * T) return;
    int n = gid / T, t = gid - n * T;
    const uint64_t* r = sw + ((size_t)n * T + t) * 8;
    uint64_t wbuf[8];
#pragma unroll
    for (int wd = 0; wd < 8; ++wd) wbuf[wd] = r[wd];
    double acc[20];
#pragma unroll
    for (int o = 0; o < 20; ++o) acc[o] = 0.0;
#pragma unroll
    for (int wd = 0; wd < 8; ++wd) {
        uint64_t mw = wbuf[wd];
        while (mw) {
            int bb = __builtin_ctzll(mw);
            const float* wp = wt + (wd * 64 + bb) * 20;
#pragma unroll
            for (int o = 0; o < 20; ++o) acc[o] += (double)wp[o];
            mw &= mw - 1;
        }
    }
#pragma unroll
    for (int o = 0; o < 20; ++o) a[(size_t)t * 1280 + n * 20 + o] = acc[o];
}

// ---------------------------------------------------------------------------
// OUT (k_out3): 24-step chunks (unchanged, R13-proven).
template<int NFULL, int TAIL>
__device__ __forceinline__ void ring_scan(const double* __restrict__ a, int row,
                                          double (*ring)[64],
                                          uint32_t (*bits)[64], int lane) {
    RC rc = make_rc();
    double y1 = 0.0, y2 = 0.0, R1 = 0.0, R2 = 0.0, dp = 0.0; uint64_t mask = 0;
    double cur[24], nxt[24];
#pragma unroll
    for (int i = 0; i < 24; ++i) cur[i] = a[(size_t)i * 1280 + row];
    for (int ch = 0; ch < NFULL; ++ch) {
        int t0 = ch * 24;
        if (ch + 1 < NFULL) {
#pragma unroll
            for (int i = 0; i < 24; ++i) nxt[i] = a[(size_t)(t0 + 24 + i) * 1280 + row];
        } else if (TAIL > 0) {
#pragma unroll
            for (int i = 0; i < 24; ++i)
                nxt[i] = (i < TAIL) ? a[(size_t)(t0 + 24 + i) * 1280 + row] : 0.0;
        }
#pragma unroll
        for (int i = 0; i < 24; ++i) ring[(t0 + i) & 127][lane] = cur[i];
        double tap[25];
#pragma unroll
        for (int i = 0; i < 25; ++i) {
            int l = t0 + i - 101;
            tap[i] = (l >= 0) ? ring[l & 127][lane] : 0.0;
        }
        uint32_t sp = 0;
#pragma unroll
        for (int i = 0; i < 24; ++i) {
            int s = rstep(rc, (i == 0) ? dp : cur[i - 1], tap[i + 1], tap[i],
                          y1, y2, R1, R2, mask);
            sp |= (uint32_t)s << i;
        }
        dp = cur[23];
        bits[ch][lane] = sp;
#pragma unroll
        for (int i = 0; i < 24; ++i) cur[i] = nxt[i];
    }
    if (TAIL > 0) {
        int t0 = NFULL * 24;
#pragma unroll
        for (int i = 0; i < 24; ++i) if (i < TAIL) ring[(t0 + i) & 127][lane] = cur[i];
        double tap[25];
#pragma unroll
        for (int i = 0; i < 25; ++i) {
            if (i > TAIL) break;
            int l = t0 + i - 101;
            tap[i] = (l >= 0) ? ring[l & 127][lane] : 0.0;
        }
        uint32_t sp = 0;
#pragma unroll
        for (int i = 0; i < 24; ++i) {
            if (i >= TAIL) break;
            int s = rstep(rc, (i == 0) ? dp : cur[i - 1], tap[i + 1], tap[i],
                          y1, y2, R1, R2, mask);
            sp |= (uint32_t)s << i;
        }
        bits[NFULL][lane] = sp;
    }
}

template<int T>
__device__ __forceinline__ void expand_bits(uint32_t (*bits)[64],
                                            float* __restrict__ out,
                                            int row0, int coff, int lane) {
    for (int r = 0; r < 64; ++r) {
        float* orow = out + (size_t)(row0 + r) * 656 + coff;
        for (int c0 = 0; c0 < T; c0 += 64) {
            int c = c0 + lane;
            if (c < T) orow[c] = (float)((bits[c / 24][r] >> (c % 24)) & 1);
        }
    }
}

__global__ __launch_bounds__(64) void k_out3(const double* __restrict__ a2,
                                             const double* __restrict__ a2b,
                                             float* __restrict__ out) {
    __shared__ double ring[128][64];
    __shared__ uint32_t bits[21][64];
    int b = blockIdx.x, lane = threadIdx.x;
    if (b < 20) {
        int row0 = b * 64;
        ring_scan<20, 20>(a2, row0 + lane, ring, bits, lane);   // 500 = 20*24+20
        expand_bits<500>(bits, out, row0, 0, lane);
    } else {
        int row0 = (b - 20) * 64;
        ring_scan<6, 12>(a2b, row0 + lane, ring, bits, lane);   // 156 = 6*24+12
        expand_bits<156>(bits, out, row0, 500, lane);
    }
}

// ---------------------------------------------------------------------------
extern "C" void kernel_launch(void* const* d_in, const int* in_sizes, int n_in,
                              void* d_out, int out_size, void* d_ws, size_t ws_size,
                              hipStream_t stream) {
    const float* x      = (const float*)d_in[0];
    const float* w_fc1  = (const float*)d_in[1];
    const float* w_fc2  = (const float*)d_in[2];
    const float* w_loc1 = (const float*)d_in[3];
    const float* w_loc2 = (const float*)d_in[4];
    const int*   perm   = (const int*)d_in[5];
    float* out = (float*)d_out;
    char* ws = (char*)d_ws;
    (void)ws_size; (void)in_sizes; (void)n_in; (void)out_size;

    // R13-proven layout (ws_size >= 114,208,768 confirmed by R13).
    double*   d1b0 = (double*)(ws + 0);             // 32,768,000 B
    double*   d1b1 = (double*)(ws + 32768000);      // 32,768,000 B
    double*   a2   = (double*)(ws + 40894464);      //  5,120,000 B (overlays d1b1; dead by then)
    double*   a2b  = (double*)(ws + 46014464);      //  1,597,440 B (overlays d1b1)
    double*   e    = (double*)(ws + 65536000);      // 40,894,464 B [n][c][512]
    uint64_t* s1w  = (uint64_t*)(ws + 106430464);   //  2,560,000 B
    uint64_t* s1bw = (uint64_t*)(ws + 108990464);   //    638,976 B
    uint64_t* xb   = (uint64_t*)(ws + 109629440);   //  1,024,000 B
    uint64_t* xbT  = (uint64_t*)(ws + 110653440);   //    638,976 B
    float*    w1t  = (float*)(ws + 111292416);      //    319,488 B
    float*    wl1t = (float*)(ws + 111611904);      //  1,024,000 B
    double*   stY1 = (double*)(ws + 112635904);     //    262,144 B
    double*   stY2 = (double*)(ws + 112898048);     //    262,144 B
    double*   stR1 = (double*)(ws + 113160192);     //    262,144 B
    double*   stR2 = (double*)(ws + 113422336);     //    262,144 B
    double*   stDp = (double*)(ws + 113684480);     //    262,144 B
    uint64_t* stM  = (uint64_t*)(ws + 113946624);   //    262,144 B

    k_prep<<<600, 256, 0, stream>>>(x, w_fc1, w_loc1, xb, xbT, w1t, wl1t);
    // sdenseA(w0) merged with sdenseB
    k_sdense0<<<35968, 256, 0, stream>>>(xb, w1t, d1b0, xbT, wl1t, e);
    // rscanA(w0) merged with rscanB
    k_rscan0<<<1024, 64, 0, stream>>>(d1b0, s1w, stY1, stY2, stR1, stR2, stDp, stM, e, perm, s1bw);
    // windows 1..3
    dim3 ga(125, 64, 2);
    for (int w = 1; w < 4; ++w) {
        double* cur  = (w & 1) ? d1b1 : d1b0;
        double* prev = (w & 1) ? d1b0 : d1b1;
        k_sdenseA<<<ga, 256, 0, stream>>>(xb, w1t, cur, w);
        k_rscanA<<<512, 64, 0, stream>>>(cur, prev, s1w, stY1, stY2, stR1, stR2, stDp, stM, w);
    }
    // layer 2
    k_dense2m<<<164, 256, 0, stream>>>(s1w, s1bw, w_fc2, w_loc2, a2, a2b);
    k_out3<<<40, 64, 0, stream>>>(a2, a2b, out);
}

// Round 16
// 403.510 us; speedup vs baseline: 1.3079x; 1.1223x over previous
//
#include <hip/hip_runtime.h>
#include <stdint.h>

#define THETA 10.0

// ---- recurrence constants (exact truncated-kernel equivalents) ------------
struct RC {
    double trs, r2s, g1, c100, c101;   // srm: trunc at k<=99
    double trr, r2r, a1c, a33, a34;    // refractory: trunc at k<=32
};
__device__ __forceinline__ RC make_rc() {
    RC c;
    double rs = exp(-0.1); c.trs = 2.0 * rs; c.r2s = rs * rs;
    c.g1 = 0.1 * exp(0.9); c.c100 = -10.0 * exp(-9.0); c.c101 = 9.9 * exp(-9.1);
    double rr = exp(-1.0); c.trr = 2.0 * rr; c.r2r = rr * rr;
    c.a1c = -20.0; c.a33 = 660.0 * exp(-32.0); c.a34 = -640.0 * exp(-33.0);
    return c;
}
__device__ __forceinline__ int rstep(const RC& c, double din, double ta, double tb,
                                     double& y1, double& y2, double& R1, double& R2,
                                     uint64_t& mask) {
    double y = c.trs * y1 - c.r2s * y2 + c.g1 * din + c.c100 * ta + c.c101 * tb;
    y2 = y1; y1 = y;
    double R = c.trr * R1 - c.r2r * R2 + c.a1c * (double)(mask & 1ull)
             + c.a33 * (double)((mask >> 32) & 1ull)
             + c.a34 * (double)((mask >> 33) & 1ull);
    R2 = R1; R1 = R;
    int s = (y + R >= THETA) ? 1 : 0;
    mask = (mask << 1) | (uint64_t)s;
    return s;
}

// ---------------------------------------------------------------------------
// PREP (unchanged, R11-proven)
__global__ __launch_bounds__(256) void k_prep(const float* __restrict__ x,
                                              const float* __restrict__ w_fc1,
                                              const float* __restrict__ w_loc1,
                                              uint64_t* __restrict__ xb,
                                              uint64_t* __restrict__ xbT,
                                              float* __restrict__ w1t,
                                              float* __restrict__ wl1t) {
    __shared__ float shf[156 * 65];
    int b = blockIdx.x, tid = threadIdx.x;
    if (b < 512) {
        int n = b >> 3, wd = b & 7;
        int t0 = wd * 64;
        for (int e = tid; e < 156 * 64; e += 256) {
            int c = e >> 6, tt = e & 63;
            int t = t0 + tt;
            shf[c * 65 + tt] = (t < 500) ? x[(size_t)n * 78000 + (size_t)c * 500 + t] : 0.0f;
        }
        __syncthreads();
        int wv = tid >> 6, lane = tid & 63;
        for (int c = wv; c < 156; c += 4) {
            uint64_t bal = __ballot(shf[c * 65 + lane] != 0.0f);
            if (lane == 0) xbT[((size_t)n * 156 + c) * 8 + wd] = bal;
        }
        if (tid < 64) {
            int t = t0 + tid;
            if (t < 500) {
                uint64_t w0 = 0, w1 = 0, w2 = 0;
#pragma unroll
                for (int c = 0; c < 156; ++c) {
                    uint64_t bit = (shf[c * 65 + tid] != 0.0f) ? 1ull : 0ull;
                    if (c < 64) w0 |= bit << c;
                    else if (c < 128) w1 |= bit << (c - 64);
                    else w2 |= bit << (c - 128);
                }
                size_t o = ((size_t)n * 500 + t) * 4;
                xb[o] = w0; xb[o + 1] = w1; xb[o + 2] = w2; xb[o + 3] = 0;
            }
        }
    } else {
        const float* src; float* dst; int C, k0, h0;
        if (b < 536) { int tk = b - 512; src = w_fc1; dst = w1t; C = 156;
                       k0 = (tk >> 3) * 64; h0 = (tk & 7) * 64; }
        else         { int tk = b - 536; src = w_loc1; dst = wl1t; C = 500;
                       k0 = (tk >> 3) * 64; h0 = (tk & 7) * 64; }
#pragma unroll
        for (int p = 0; p < 16; ++p) {
            int e = tid + p * 256;
            int hh = e >> 6, kk = e & 63;
            int k = k0 + kk;
            shf[hh * 65 + kk] = (k < C) ? src[(size_t)(h0 + hh) * C + k] : 0.0f;
        }
        __syncthreads();
#pragma unroll
        for (int p = 0; p < 16; ++p) {
            int e = tid + p * 256;
            int hh = e & 63, kk = e >> 6;
            int k = k0 + kk;
            if (k < C) dst[(size_t)k * 512 + h0 + hh] = shf[hh * 65 + kk];
        }
    }
}

// ---------------------------------------------------------------------------
// Dual-h serial gather: one mask walk feeds TWO h positions (h, h+256) ->
// 2 independent coalesced loads in flight per bit, mask VALU unchanged,
// per-h accumulation order bit-identical to the serial walk.
__device__ __forceinline__ void sdenseA_body2(const uint64_t* __restrict__ xb,
                                              const float* __restrict__ w1t,
                                              double* __restrict__ d1w,
                                              int w, int tl, int n, int h) {
    const uint64_t* mb = xb + ((size_t)n * 500 + w * 125 + tl) * 4;
    uint64_t m0 = mb[0], m1 = mb[1], m2 = mb[2];
    double a0 = 0.0, a1 = 0.0, a2 = 0.0;
    double b0 = 0.0, b1 = 0.0, b2 = 0.0;
    while (m0) {
        int bb = __builtin_ctzll(m0);
        const float* p = w1t + (size_t)bb * 512;
        a0 += (double)p[h]; b0 += (double)p[h + 256];
        m0 &= m0 - 1;
    }
    while (m1) {
        int bb = __builtin_ctzll(m1);
        const float* p = w1t + (size_t)(64 + bb) * 512;
        a1 += (double)p[h]; b1 += (double)p[h + 256];
        m1 &= m1 - 1;
    }
    while (m2) {
        int bb = __builtin_ctzll(m2);
        const float* p = w1t + (size_t)(128 + bb) * 512;
        a2 += (double)p[h]; b2 += (double)p[h + 256];
        m2 &= m2 - 1;
    }
    size_t base = (size_t)tl * 32768 + n * 512;
    d1w[base + h] = (a0 + a1) + a2;
    d1w[base + h + 256] = (b0 + b1) + b2;
}

__device__ __forceinline__ void sdenseB_body2(const uint64_t* __restrict__ xbT,
                                              const float* __restrict__ wl1t,
                                              double* __restrict__ e,
                                              int c, int n, int h) {
    const uint64_t* mb = xbT + ((size_t)n * 156 + c) * 8;
    double da = 0.0, db = 0.0;
#pragma unroll
    for (int wd = 0; wd < 8; ++wd) {
        uint64_t mw = mb[wd];
        const float* wbase = wl1t + (size_t)wd * 64 * 512;
        while (mw) {
            int bb = __builtin_ctzll(mw);
            const float* p = wbase + (size_t)bb * 512;
            da += (double)p[h]; db += (double)p[h + 256];
            mw &= mw - 1;
        }
    }
    size_t base = ((size_t)n * 156 + c) * 512;
    e[base + h] = da;
    e[base + h + 256] = db;
}

// A1 (windows 1..3): grid (125,64) x 256, dual-h
__global__ __launch_bounds__(256) void k_sdenseA(const uint64_t* __restrict__ xb,
                                                 const float* __restrict__ w1t,
                                                 double* __restrict__ d1w, int w) {
    sdenseA_body2(xb, w1t, d1w, w, blockIdx.x, blockIdx.y, threadIdx.x);
}

// Merged sdenseA(w0) + sdenseB: one dispatch, 17984 blocks x 256
__global__ __launch_bounds__(256) void k_sdense0(const uint64_t* __restrict__ xb,
                                                 const float* __restrict__ w1t,
                                                 double* __restrict__ d1w,
                                                 const uint64_t* __restrict__ xbT,
                                                 const float* __restrict__ wl1t,
                                                 double* __restrict__ e) {
    int b = blockIdx.x, tid = threadIdx.x;
    if (b < 8000) {
        int tl = b % 125, n = b / 125;
        sdenseA_body2(xb, w1t, d1w, 0, tl, n, tid);
    } else {
        int idx = b - 8000;                     // [0, 9984)
        int c = idx % 156, n = idx / 156;
        sdenseB_body2(xbT, wl1t, e, c, n, tid);
    }
}

// ---- rscanA body (ring pattern, 12-deep, R13-verified) ---------------------
__device__ __forceinline__ void rscanA_body(const double* __restrict__ cur,
                                            const double* __restrict__ prev,
                                            uint64_t* __restrict__ s1w,
                                            double* stY1, double* stY2,
                                            double* stR1, double* stR2,
                                            double* stDp, uint64_t* stM,
                                            int w, int lane, int blk,
                                            double (*ring)[64]) {
    int gid = blk * 64 + lane;                  // n*512 + h
    int n = gid >> 9, word = (gid >> 6) & 7;
    RC rc = make_rc();
    int t0g = w * 125;
    double y1, y2, R1, R2, dp; uint64_t mask;
    if (w == 0) { y1 = y2 = R1 = R2 = dp = 0.0; mask = 0; }
    else {
        y1 = stY1[gid]; y2 = stY2[gid]; R1 = stR1[gid]; R2 = stR2[gid];
        dp = stDp[gid]; mask = stM[gid];
#pragma unroll 4
        for (int k = 0; k < 101; ++k)
            ring[(t0g - 101 + k) & 127][lane] = prev[(size_t)(24 + k) * 32768 + gid];
    }
    double curv[12], nxt[12];
#pragma unroll
    for (int i = 0; i < 12; ++i) curv[i] = cur[(size_t)i * 32768 + gid];
    for (int ch = 0; ch < 10; ++ch) {
        int b0 = ch * 12;
#pragma unroll
        for (int i = 0; i < 12; ++i) {
            int l = b0 + 12 + i;
            nxt[i] = (l < 125) ? cur[(size_t)l * 32768 + gid] : 0.0;
        }
#pragma unroll
        for (int i = 0; i < 12; ++i) ring[(t0g + b0 + i) & 127][lane] = curv[i];
#pragma unroll
        for (int i = 0; i < 12; ++i) {
            int tg = t0g + b0 + i;
            double ta = (tg >= 100) ? ring[(tg - 100) & 127][lane] : 0.0;
            double tb = (tg >= 101) ? ring[(tg - 101) & 127][lane] : 0.0;
            int s = rstep(rc, (i == 0) ? dp : curv[i - 1], ta, tb, y1, y2, R1, R2, mask);
            uint64_t bal = __ballot(s != 0);
            if (lane == 0) s1w[((size_t)n * 500 + tg) * 8 + word] = bal;
        }
        dp = curv[11];
#pragma unroll
        for (int i = 0; i < 12; ++i) curv[i] = nxt[i];
    }
#pragma unroll
    for (int i = 0; i < 5; ++i) ring[(t0g + 120 + i) & 127][lane] = curv[i];
#pragma unroll
    for (int i = 0; i < 5; ++i) {
        int tg = t0g + 120 + i;
        double ta = ring[(tg - 100) & 127][lane];
        double tb = ring[(tg - 101) & 127][lane];
        int s = rstep(rc, (i == 0) ? dp : curv[i - 1], ta, tb, y1, y2, R1, R2, mask);
        uint64_t bal = __ballot(s != 0);
        if (lane == 0) s1w[((size_t)n * 500 + tg) * 8 + word] = bal;
    }
    dp = curv[4];
    stY1[gid] = y1; stY2[gid] = y2; stR1[gid] = R1; stR2[gid] = R2;
    stDp[gid] = dp; stM[gid] = mask;
}

__device__ __forceinline__ void rscanB_body(const double* __restrict__ e,
                                            const int* pl,
                                            uint64_t* __restrict__ s1bw,
                                            int lane, int blk,
                                            double (*ring)[64]) {
    int gid = blk * 64 + lane;                  // n*512 + h
    int n = gid >> 9, h = gid & 511, word = (gid >> 6) & 7;
    const double* en = e + (size_t)n * 156 * 512;
    RC rc = make_rc();
    double y1 = 0.0, y2 = 0.0, R1 = 0.0, R2 = 0.0, dp = 0.0; uint64_t mask = 0;
    double curv[12], nxt[12];
#pragma unroll
    for (int i = 0; i < 12; ++i) curv[i] = en[(size_t)pl[i] * 512 + h];
    for (int ch = 0; ch < 13; ++ch) {
        int b0 = ch * 12;
        if (ch < 12) {
#pragma unroll
            for (int i = 0; i < 12; ++i) nxt[i] = en[(size_t)pl[b0 + 12 + i] * 512 + h];
        }
#pragma unroll
        for (int i = 0; i < 12; ++i) ring[(b0 + i) & 127][lane] = curv[i];
#pragma unroll
        for (int i = 0; i < 12; ++i) {
            int j = b0 + i;
            double ta = (j >= 100) ? ring[(j - 100) & 127][lane] : 0.0;
            double tb = (j >= 101) ? ring[(j - 101) & 127][lane] : 0.0;
            int s = rstep(rc, (i == 0) ? dp : curv[i - 1], ta, tb, y1, y2, R1, R2, mask);
            uint64_t bal = __ballot(s != 0);
            if (lane == 0) s1bw[((size_t)n * 156 + j) * 8 + word] = bal;
        }
        dp = curv[11];
#pragma unroll
        for (int i = 0; i < 12; ++i) curv[i] = nxt[i];
    }
}

// rscanA windows 1..3 (512 blocks x 64)
__global__ __launch_bounds__(64) void k_rscanA(const double* __restrict__ cur,
                                               const double* __restrict__ prev,
                                               uint64_t* __restrict__ s1w,
                                               double* stY1, double* stY2,
                                               double* stR1, double* stR2,
                                               double* stDp, uint64_t* stM, int w) {
    __shared__ double ring[128][64];
    rscanA_body(cur, prev, s1w, stY1, stY2, stR1, stR2, stDp, stM,
                w, threadIdx.x, blockIdx.x, ring);
}

// Merged rscanA(w0) + rscanB: 1024 blocks x 64
__global__ __launch_bounds__(64) void k_rscan0(const double* __restrict__ cur,
                                               uint64_t* __restrict__ s1w,
                                               double* stY1, double* stY2,
                                               double* stR1, double* stR2,
                                               double* stDp, uint64_t* stM,
                                               const double* __restrict__ e,
                                               const int* __restrict__ perm,
                                               uint64_t* __restrict__ s1bw) {
    __shared__ double ring[128][64];
    __shared__ int pl[156];
    int b = blockIdx.x, lane = threadIdx.x;
    if (b < 512) {
        rscanA_body(cur, cur, s1w, stY1, stY2, stR1, stR2, stDp, stM,
                    0, lane, b, ring);
    } else {
        for (int i = lane; i < 156; i += 64) pl[i] = perm[i];
        __syncthreads();
        rscanB_body(e, pl, s1bw, lane, b - 512, ring);
    }
}

// ---------------------------------------------------------------------------
// DENSE2 (merged A+B): a2[t][1280], a2b[j][1280], col = n*20+o. (unchanged)
__global__ __launch_bounds__(256) void k_dense2m(const uint64_t* __restrict__ s1w,
                                                 const uint64_t* __restrict__ s1bw,
                                                 const float* __restrict__ w_fc2,
                                                 const float* __restrict__ w_loc2,
                                                 double* __restrict__ a2,
                                                 double* __restrict__ a2b) {
    __shared__ float wt[512 * 20];
    int b = blockIdx.x, tid = threadIdx.x;
    int isA = (b < 125);
    const float* w = isA ? w_fc2 : w_loc2;
    const uint64_t* sw = isA ? s1w : s1bw;
    double* a = isA ? a2 : a2b;
    int T = isA ? 500 : 156;
    int gid = (isA ? b : (b - 125)) * 256 + tid;
    for (int e = tid; e < 512 * 20; e += 256) { int o = e / 512, hh = e % 512; wt[hh * 20 + o] = w[e]; }
    __syncthreads();
    if (gid >= 64 * T) return;
    int n = gid / T, t = gid - n * T;
    const uint64_t* r = sw + ((size_t)n * T + t) * 8;
    uint64_t wbuf[8];
#pragma unroll
    for (int wd = 0; wd < 8; ++wd) wbuf[wd] = r[wd];
    double acc[20];
#pragma unroll
    for (int o = 0; o < 20; ++o) acc[o] = 0.0;
#pragma unroll
    for (int wd = 0; wd < 8; ++wd) {
        uint64_t mw = wbuf[wd];
        while (mw) {
            int bb = __builtin_ctzll(mw);
            const float* wp = wt + (wd * 64 + bb) * 20;
#pragma unroll
            for (int o = 0; o < 20; ++o) acc[o] += (double)wp[o];
            mw &= mw - 1;
        }
    }
#pragma unroll
    for (int o = 0; o < 20; ++o) a[(size_t)t * 1280 + n * 20 + o] = acc[o];
}

// ---------------------------------------------------------------------------
// OUT (k_out3): 24-step chunks (unchanged, R13-proven).
template<int NFULL, int TAIL>
__device__ __forceinline__ void ring_scan(const double* __restrict__ a, int row,
                                          double (*ring)[64],
                                          uint32_t (*bits)[64], int lane) {
    RC rc = make_rc();
    double y1 = 0.0, y2 = 0.0, R1 = 0.0, R2 = 0.0, dp = 0.0; uint64_t mask = 0;
    double cur[24], nxt[24];
#pragma unroll
    for (int i = 0; i < 24; ++i) cur[i] = a[(size_t)i * 1280 + row];
    for (int ch = 0; ch < NFULL; ++ch) {
        int t0 = ch * 24;
        if (ch + 1 < NFULL) {
#pragma unroll
            for (int i = 0; i < 24; ++i) nxt[i] = a[(size_t)(t0 + 24 + i) * 1280 + row];
        } else if (TAIL > 0) {
#pragma unroll
            for (int i = 0; i < 24; ++i)
                nxt[i] = (i < TAIL) ? a[(size_t)(t0 + 24 + i) * 1280 + row] : 0.0;
        }
#pragma unroll
        for (int i = 0; i < 24; ++i) ring[(t0 + i) & 127][lane] = cur[i];
        double tap[25];
#pragma unroll
        for (int i = 0; i < 25; ++i) {
            int l = t0 + i - 101;
            tap[i] = (l >= 0) ? ring[l & 127][lane] : 0.0;
        }
        uint32_t sp = 0;
#pragma unroll
        for (int i = 0; i < 24; ++i) {
            int s = rstep(rc, (i == 0) ? dp : cur[i - 1], tap[i + 1], tap[i],
                          y1, y2, R1, R2, mask);
            sp |= (uint32_t)s << i;
        }
        dp = cur[23];
        bits[ch][lane] = sp;
#pragma unroll
        for (int i = 0; i < 24; ++i) cur[i] = nxt[i];
    }
    if (TAIL > 0) {
        int t0 = NFULL * 24;
#pragma unroll
        for (int i = 0; i < 24; ++i) if (i < TAIL) ring[(t0 + i) & 127][lane] = cur[i];
        double tap[25];
#pragma unroll
        for (int i = 0; i < 25; ++i) {
            if (i > TAIL) break;
            int l = t0 + i - 101;
            tap[i] = (l >= 0) ? ring[l & 127][lane] : 0.0;
        }
        uint32_t sp = 0;
#pragma unroll
        for (int i = 0; i < 24; ++i) {
            if (i >= TAIL) break;
            int s = rstep(rc, (i == 0) ? dp : cur[i - 1], tap[i + 1], tap[i],
                          y1, y2, R1, R2, mask);
            sp |= (uint32_t)s << i;
        }
        bits[NFULL][lane] = sp;
    }
}

template<int T>
__device__ __forceinline__ void expand_bits(uint32_t (*bits)[64],
                                            float* __restrict__ out,
                                            int row0, int coff, int lane) {
    for (int r = 0; r < 64; ++r) {
        float* orow = out + (size_t)(row0 + r) * 656 + coff;
        for (int c0 = 0; c0 < T; c0 += 64) {
            int c = c0 + lane;
            if (c < T) orow[c] = (float)((bits[c / 24][r] >> (c % 24)) & 1);
        }
    }
}

__global__ __launch_bounds__(64) void k_out3(const double* __restrict__ a2,
                                             const double* __restrict__ a2b,
                                             float* __restrict__ out) {
    __shared__ double ring[128][64];
    __shared__ uint32_t bits[21][64];
    int b = blockIdx.x, lane = threadIdx.x;
    if (b < 20) {
        int row0 = b * 64;
        ring_scan<20, 20>(a2, row0 + lane, ring, bits, lane);   // 500 = 20*24+20
        expand_bits<500>(bits, out, row0, 0, lane);
    } else {
        int row0 = (b - 20) * 64;
        ring_scan<6, 12>(a2b, row0 + lane, ring, bits, lane);   // 156 = 6*24+12
        expand_bits<156>(bits, out, row0, 500, lane);
    }
}

// ---------------------------------------------------------------------------
extern "C" void kernel_launch(void* const* d_in, const int* in_sizes, int n_in,
                              void* d_out, int out_size, void* d_ws, size_t ws_size,
                              hipStream_t stream) {
    const float* x      = (const float*)d_in[0];
    const float* w_fc1  = (const float*)d_in[1];
    const float* w_fc2  = (const float*)d_in[2];
    const float* w_loc1 = (const float*)d_in[3];
    const float* w_loc2 = (const float*)d_in[4];
    const int*   perm   = (const int*)d_in[5];
    float* out = (float*)d_out;
    char* ws = (char*)d_ws;
    (void)ws_size; (void)in_sizes; (void)n_in; (void)out_size;

    // R13-proven layout (ws_size >= 114,208,768 confirmed by R13).
    double*   d1b0 = (double*)(ws + 0);             // 32,768,000 B
    double*   d1b1 = (double*)(ws + 32768000);      // 32,768,000 B
    double*   a2   = (double*)(ws + 40894464);      //  5,120,000 B (overlays d1b1; dead by then)
    double*   a2b  = (double*)(ws + 46014464);      //  1,597,440 B (overlays d1b1)
    double*   e    = (double*)(ws + 65536000);      // 40,894,464 B [n][c][512]
    uint64_t* s1w  = (uint64_t*)(ws + 106430464);   //  2,560,000 B
    uint64_t* s1bw = (uint64_t*)(ws + 108990464);   //    638,976 B
    uint64_t* xb   = (uint64_t*)(ws + 109629440);   //  1,024,000 B
    uint64_t* xbT  = (uint64_t*)(ws + 110653440);   //    638,976 B
    float*    w1t  = (float*)(ws + 111292416);      //    319,488 B
    float*    wl1t = (float*)(ws + 111611904);      //  1,024,000 B
    double*   stY1 = (double*)(ws + 112635904);     //    262,144 B
    double*   stY2 = (double*)(ws + 112898048);     //    262,144 B
    double*   stR1 = (double*)(ws + 113160192);     //    262,144 B
    double*   stR2 = (double*)(ws + 113422336);     //    262,144 B
    double*   stDp = (double*)(ws + 113684480);     //    262,144 B
    uint64_t* stM  = (uint64_t*)(ws + 113946624);   //    262,144 B

    k_prep<<<600, 256, 0, stream>>>(x, w_fc1, w_loc1, xb, xbT, w1t, wl1t);
    // sdenseA(w0) merged with sdenseB (dual-h bodies)
    k_sdense0<<<17984, 256, 0, stream>>>(xb, w1t, d1b0, xbT, wl1t, e);
    // rscanA(w0) merged with rscanB
    k_rscan0<<<1024, 64, 0, stream>>>(d1b0, s1w, stY1, stY2, stR1, stR2, stDp, stM, e, perm, s1bw);
    // windows 1..3
    dim3 ga(125, 64);
    for (int w = 1; w < 4; ++w) {
        double* cur  = (w & 1) ? d1b1 : d1b0;
        double* prev = (w & 1) ? d1b0 : d1b1;
        k_sdenseA<<<ga, 256, 0, stream>>>(xb, w1t, cur, w);
        k_rscanA<<<512, 64, 0, stream>>>(cur, prev, s1w, stY1, stY2, stR1, stR2, stDp, stM, w);
    }
    // layer 2
    k_dense2m<<<164, 256, 0, stream>>>(s1w, s1bw, w_fc2, w_loc2, a2, a2b);
    k_out3<<<40, 64, 0, stream>>>(a2, a2b, out);
}

// Round 17
// 327.929 us; speedup vs baseline: 1.6094x; 1.2305x over previous
//
#include <hip/hip_runtime.h>
#include <stdint.h>

#define THETA 10.0

// ---- recurrence constants (exact truncated-kernel equivalents) ------------
struct RC {
    double trs, r2s, g1, c100, c101;   // srm: trunc at k<=99
    double trr, r2r, a1c, a33, a34;    // refractory: trunc at k<=32
};
__device__ __forceinline__ RC make_rc() {
    RC c;
    double rs = exp(-0.1); c.trs = 2.0 * rs; c.r2s = rs * rs;
    c.g1 = 0.1 * exp(0.9); c.c100 = -10.0 * exp(-9.0); c.c101 = 9.9 * exp(-9.1);
    double rr = exp(-1.0); c.trr = 2.0 * rr; c.r2r = rr * rr;
    c.a1c = -20.0; c.a33 = 660.0 * exp(-32.0); c.a34 = -640.0 * exp(-33.0);
    return c;
}
__device__ __forceinline__ int rstep(const RC& c, double din, double ta, double tb,
                                     double& y1, double& y2, double& R1, double& R2,
                                     uint64_t& mask) {
    double y = c.trs * y1 - c.r2s * y2 + c.g1 * din + c.c100 * ta + c.c101 * tb;
    y2 = y1; y1 = y;
    double R = c.trr * R1 - c.r2r * R2 + c.a1c * (double)(mask & 1ull)
             + c.a33 * (double)((mask >> 32) & 1ull)
             + c.a34 * (double)((mask >> 33) & 1ull);
    R2 = R1; R1 = R;
    int s = (y + R >= THETA) ? 1 : 0;
    mask = (mask << 1) | (uint64_t)s;
    return s;
}

// ---------------------------------------------------------------------------
// PREP (unchanged, R11-proven)
__global__ __launch_bounds__(256) void k_prep(const float* __restrict__ x,
                                              const float* __restrict__ w_fc1,
                                              const float* __restrict__ w_loc1,
                                              uint64_t* __restrict__ xb,
                                              uint64_t* __restrict__ xbT,
                                              float* __restrict__ w1t,
                                              float* __restrict__ wl1t) {
    __shared__ float shf[156 * 65];
    int b = blockIdx.x, tid = threadIdx.x;
    if (b < 512) {
        int n = b >> 3, wd = b & 7;
        int t0 = wd * 64;
        for (int e = tid; e < 156 * 64; e += 256) {
            int c = e >> 6, tt = e & 63;
            int t = t0 + tt;
            shf[c * 65 + tt] = (t < 500) ? x[(size_t)n * 78000 + (size_t)c * 500 + t] : 0.0f;
        }
        __syncthreads();
        int wv = tid >> 6, lane = tid & 63;
        for (int c = wv; c < 156; c += 4) {
            uint64_t bal = __ballot(shf[c * 65 + lane] != 0.0f);
            if (lane == 0) xbT[((size_t)n * 156 + c) * 8 + wd] = bal;
        }
        if (tid < 64) {
            int t = t0 + tid;
            if (t < 500) {
                uint64_t w0 = 0, w1 = 0, w2 = 0;
#pragma unroll
                for (int c = 0; c < 156; ++c) {
                    uint64_t bit = (shf[c * 65 + tid] != 0.0f) ? 1ull : 0ull;
                    if (c < 64) w0 |= bit << c;
                    else if (c < 128) w1 |= bit << (c - 64);
                    else w2 |= bit << (c - 128);
                }
                size_t o = ((size_t)n * 500 + t) * 4;
                xb[o] = w0; xb[o + 1] = w1; xb[o + 2] = w2; xb[o + 3] = 0;
            }
        }
    } else {
        const float* src; float* dst; int C, k0, h0;
        if (b < 536) { int tk = b - 512; src = w_fc1; dst = w1t; C = 156;
                       k0 = (tk >> 3) * 64; h0 = (tk & 7) * 64; }
        else         { int tk = b - 536; src = w_loc1; dst = wl1t; C = 500;
                       k0 = (tk >> 3) * 64; h0 = (tk & 7) * 64; }
#pragma unroll
        for (int p = 0; p < 16; ++p) {
            int e = tid + p * 256;
            int hh = e >> 6, kk = e & 63;
            int k = k0 + kk;
            shf[hh * 65 + kk] = (k < C) ? src[(size_t)(h0 + hh) * C + k] : 0.0f;
        }
        __syncthreads();
#pragma unroll
        for (int p = 0; p < 16; ++p) {
            int e = tid + p * 256;
            int hh = e & 63, kk = e >> 6;
            int k = k0 + kk;
            if (k < C) dst[(size_t)k * 512 + h0 + hh] = shf[hh * 65 + kk];
        }
    }
}

// ---------------------------------------------------------------------------
// Quad-h serial gather: one mask walk feeds FOUR h positions (h+128q) ->
// 4 independent coalesced loads in flight per bit, mask VALU unchanged,
// per-h accumulation order bit-identical to the serial walk.
__device__ __forceinline__ void sdenseA_body4(const uint64_t* __restrict__ xb,
                                              const float* __restrict__ w1t,
                                              double* __restrict__ d1w,
                                              int tl, int n, int h) {
    const uint64_t* mb = xb + ((size_t)n * 500 + tl) * 4;
    uint64_t m0 = mb[0], m1 = mb[1], m2 = mb[2];
    double acc[4][3];
#pragma unroll
    for (int q = 0; q < 4; ++q) { acc[q][0] = 0.0; acc[q][1] = 0.0; acc[q][2] = 0.0; }
    while (m0) {
        int bb = __builtin_ctzll(m0);
        const float* p = w1t + (size_t)bb * 512 + h;
#pragma unroll
        for (int q = 0; q < 4; ++q) acc[q][0] += (double)p[q * 128];
        m0 &= m0 - 1;
    }
    while (m1) {
        int bb = __builtin_ctzll(m1);
        const float* p = w1t + (size_t)(64 + bb) * 512 + h;
#pragma unroll
        for (int q = 0; q < 4; ++q) acc[q][1] += (double)p[q * 128];
        m1 &= m1 - 1;
    }
    while (m2) {
        int bb = __builtin_ctzll(m2);
        const float* p = w1t + (size_t)(128 + bb) * 512 + h;
#pragma unroll
        for (int q = 0; q < 4; ++q) acc[q][2] += (double)p[q * 128];
        m2 &= m2 - 1;
    }
    size_t base = (size_t)tl * 32768 + n * 512;
#pragma unroll
    for (int q = 0; q < 4; ++q)
        d1w[base + h + q * 128] = (acc[q][0] + acc[q][1]) + acc[q][2];
}

__device__ __forceinline__ void sdenseB_body4(const uint64_t* __restrict__ xbT,
                                              const float* __restrict__ wl1t,
                                              double* __restrict__ e,
                                              int c, int n, int h) {
    const uint64_t* mb = xbT + ((size_t)n * 156 + c) * 8;
    double acc[4];
#pragma unroll
    for (int q = 0; q < 4; ++q) acc[q] = 0.0;
#pragma unroll
    for (int wd = 0; wd < 8; ++wd) {
        uint64_t mw = mb[wd];
        const float* wbase = wl1t + (size_t)wd * 64 * 512 + h;
        while (mw) {
            int bb = __builtin_ctzll(mw);
            const float* p = wbase + (size_t)bb * 512;
#pragma unroll
            for (int q = 0; q < 4; ++q) acc[q] += (double)p[q * 128];
            mw &= mw - 1;
        }
    }
    size_t base = ((size_t)n * 156 + c) * 512;
#pragma unroll
    for (int q = 0; q < 4; ++q) e[base + h + q * 128] = acc[q];
}

// ---- MAIN path: all 500 t in one dispatch + B. 41984 blocks x 128. --------
__global__ __launch_bounds__(128) void k_sdense_full(const uint64_t* __restrict__ xb,
                                                     const float* __restrict__ w1t,
                                                     double* __restrict__ d1,
                                                     const uint64_t* __restrict__ xbT,
                                                     const float* __restrict__ wl1t,
                                                     double* __restrict__ e) {
    int b = blockIdx.x, h = threadIdx.x;
    if (b < 32000) {
        int tl = b % 500, n = b / 500;
        sdenseA_body4(xb, w1t, d1, tl, n, h);
    } else {
        int idx = b - 32000;
        int c = idx % 156, n = idx / 156;
        sdenseB_body4(xbT, wl1t, e, c, n, h);
    }
}

// ---- FALLBACK kernels (R16 window structure, quad-h bodies) ---------------
__global__ __launch_bounds__(128) void k_sdenseA_fb(const uint64_t* __restrict__ xb,
                                                    const float* __restrict__ w1t,
                                                    double* __restrict__ d1w, int w) {
    sdenseA_body4(xb, w1t, d1w - (size_t)w * 125 * 32768, w * 125 + blockIdx.x,
                  blockIdx.y, threadIdx.x);
}
__global__ __launch_bounds__(128) void k_sdense0_fb(const uint64_t* __restrict__ xb,
                                                    const float* __restrict__ w1t,
                                                    double* __restrict__ d1w,
                                                    const uint64_t* __restrict__ xbT,
                                                    const float* __restrict__ wl1t,
                                                    double* __restrict__ e) {
    int b = blockIdx.x, h = threadIdx.x;
    if (b < 8000) {
        int tl = b % 125, n = b / 125;
        sdenseA_body4(xb, w1t, d1w, tl, n, h);
    } else {
        int idx = b - 8000;
        int c = idx % 156, n = idx / 156;
        sdenseB_body4(xbT, wl1t, e, c, n, h);
    }
}

// ---- rscan bodies ----------------------------------------------------------
__device__ __forceinline__ void rscanA_body(const double* __restrict__ cur,
                                            const double* __restrict__ prev,
                                            uint64_t* __restrict__ s1w,
                                            double* stY1, double* stY2,
                                            double* stR1, double* stR2,
                                            double* stDp, uint64_t* stM,
                                            int w, int lane, int blk,
                                            double (*ring)[64]) {
    int gid = blk * 64 + lane;                  // n*512 + h
    int n = gid >> 9, word = (gid >> 6) & 7;
    RC rc = make_rc();
    int t0g = w * 125;
    double y1, y2, R1, R2, dp; uint64_t mask;
    if (w == 0) { y1 = y2 = R1 = R2 = dp = 0.0; mask = 0; }
    else {
        y1 = stY1[gid]; y2 = stY2[gid]; R1 = stR1[gid]; R2 = stR2[gid];
        dp = stDp[gid]; mask = stM[gid];
#pragma unroll 4
        for (int k = 0; k < 101; ++k)
            ring[(t0g - 101 + k) & 127][lane] = prev[(size_t)(24 + k) * 32768 + gid];
    }
    double curv[12], nxt[12];
#pragma unroll
    for (int i = 0; i < 12; ++i) curv[i] = cur[(size_t)i * 32768 + gid];
    for (int ch = 0; ch < 10; ++ch) {
        int b0 = ch * 12;
#pragma unroll
        for (int i = 0; i < 12; ++i) {
            int l = b0 + 12 + i;
            nxt[i] = (l < 125) ? cur[(size_t)l * 32768 + gid] : 0.0;
        }
#pragma unroll
        for (int i = 0; i < 12; ++i) ring[(t0g + b0 + i) & 127][lane] = curv[i];
#pragma unroll
        for (int i = 0; i < 12; ++i) {
            int tg = t0g + b0 + i;
            double ta = (tg >= 100) ? ring[(tg - 100) & 127][lane] : 0.0;
            double tb = (tg >= 101) ? ring[(tg - 101) & 127][lane] : 0.0;
            int s = rstep(rc, (i == 0) ? dp : curv[i - 1], ta, tb, y1, y2, R1, R2, mask);
            uint64_t bal = __ballot(s != 0);
            if (lane == 0) s1w[((size_t)n * 500 + tg) * 8 + word] = bal;
        }
        dp = curv[11];
#pragma unroll
        for (int i = 0; i < 12; ++i) curv[i] = nxt[i];
    }
#pragma unroll
    for (int i = 0; i < 5; ++i) ring[(t0g + 120 + i) & 127][lane] = curv[i];
#pragma unroll
    for (int i = 0; i < 5; ++i) {
        int tg = t0g + 120 + i;
        double ta = ring[(tg - 100) & 127][lane];
        double tb = ring[(tg - 101) & 127][lane];
        int s = rstep(rc, (i == 0) ? dp : curv[i - 1], ta, tb, y1, y2, R1, R2, mask);
        uint64_t bal = __ballot(s != 0);
        if (lane == 0) s1w[((size_t)n * 500 + tg) * 8 + word] = bal;
    }
    dp = curv[4];
    stY1[gid] = y1; stY2[gid] = y2; stR1[gid] = R1; stR2[gid] = R2;
    stDp[gid] = dp; stM[gid] = mask;
}

__device__ __forceinline__ void rscanB_body(const double* __restrict__ e,
                                            const int* pl,
                                            uint64_t* __restrict__ s1bw,
                                            int lane, int blk,
                                            double (*ring)[64]) {
    int gid = blk * 64 + lane;                  // n*512 + h
    int n = gid >> 9, h = gid & 511, word = (gid >> 6) & 7;
    const double* en = e + (size_t)n * 156 * 512;
    RC rc = make_rc();
    double y1 = 0.0, y2 = 0.0, R1 = 0.0, R2 = 0.0, dp = 0.0; uint64_t mask = 0;
    double curv[12], nxt[12];
#pragma unroll
    for (int i = 0; i < 12; ++i) curv[i] = en[(size_t)pl[i] * 512 + h];
    for (int ch = 0; ch < 13; ++ch) {
        int b0 = ch * 12;
        if (ch < 12) {
#pragma unroll
            for (int i = 0; i < 12; ++i) nxt[i] = en[(size_t)pl[b0 + 12 + i] * 512 + h];
        }
#pragma unroll
        for (int i = 0; i < 12; ++i) ring[(b0 + i) & 127][lane] = curv[i];
#pragma unroll
        for (int i = 0; i < 12; ++i) {
            int j = b0 + i;
            double ta = (j >= 100) ? ring[(j - 100) & 127][lane] : 0.0;
            double tb = (j >= 101) ? ring[(j - 101) & 127][lane] : 0.0;
            int s = rstep(rc, (i == 0) ? dp : curv[i - 1], ta, tb, y1, y2, R1, R2, mask);
            uint64_t bal = __ballot(s != 0);
            if (lane == 0) s1bw[((size_t)n * 156 + j) * 8 + word] = bal;
        }
        dp = curv[11];
#pragma unroll
        for (int i = 0; i < 12; ++i) curv[i] = nxt[i];
    }
}

// MAIN: full 500-step A scan (no checkpoints/preloads) merged with B scan.
__global__ __launch_bounds__(64) void k_rscan_full(const double* __restrict__ d1,
                                                   uint64_t* __restrict__ s1w,
                                                   const double* __restrict__ e,
                                                   const int* __restrict__ perm,
                                                   uint64_t* __restrict__ s1bw) {
    __shared__ double ring[128][64];
    __shared__ int pl[156];
    int b = blockIdx.x, lane = threadIdx.x;
    if (b < 512) {
        int gid = b * 64 + lane;                // n*512 + h
        int n = gid >> 9, word = (gid >> 6) & 7;
        RC rc = make_rc();
        double y1 = 0.0, y2 = 0.0, R1 = 0.0, R2 = 0.0, dp = 0.0; uint64_t mask = 0;
        double curv[12], nxt[12];
#pragma unroll
        for (int i = 0; i < 12; ++i) curv[i] = d1[(size_t)i * 32768 + gid];
        for (int ch = 0; ch < 41; ++ch) {
            int b0 = ch * 12;
#pragma unroll
            for (int i = 0; i < 12; ++i) {
                int l = b0 + 12 + i;
                nxt[i] = (l < 500) ? d1[(size_t)l * 32768 + gid] : 0.0;
            }
#pragma unroll
            for (int i = 0; i < 12; ++i) ring[(b0 + i) & 127][lane] = curv[i];
#pragma unroll
            for (int i = 0; i < 12; ++i) {
                int tg = b0 + i;
                double ta = (tg >= 100) ? ring[(tg - 100) & 127][lane] : 0.0;
                double tb = (tg >= 101) ? ring[(tg - 101) & 127][lane] : 0.0;
                int s = rstep(rc, (i == 0) ? dp : curv[i - 1], ta, tb, y1, y2, R1, R2, mask);
                uint64_t bal = __ballot(s != 0);
                if (lane == 0) s1w[((size_t)n * 500 + tg) * 8 + word] = bal;
            }
            dp = curv[11];
#pragma unroll
            for (int i = 0; i < 12; ++i) curv[i] = nxt[i];
        }
        // tail: t 492..499 in curv[0..7]
#pragma unroll
        for (int i = 0; i < 8; ++i) ring[(492 + i) & 127][lane] = curv[i];
#pragma unroll
        for (int i = 0; i < 8; ++i) {
            int tg = 492 + i;
            double ta = ring[(tg - 100) & 127][lane];
            double tb = ring[(tg - 101) & 127][lane];
            int s = rstep(rc, (i == 0) ? dp : curv[i - 1], ta, tb, y1, y2, R1, R2, mask);
            uint64_t bal = __ballot(s != 0);
            if (lane == 0) s1w[((size_t)n * 500 + tg) * 8 + word] = bal;
        }
    } else {
        for (int i = lane; i < 156; i += 64) pl[i] = perm[i];
        __syncthreads();
        rscanB_body(e, pl, s1bw, lane, b - 512, ring);
    }
}

// FALLBACK rscan kernels (R16-identical)
__global__ __launch_bounds__(64) void k_rscanA(const double* __restrict__ cur,
                                               const double* __restrict__ prev,
                                               uint64_t* __restrict__ s1w,
                                               double* stY1, double* stY2,
                                               double* stR1, double* stR2,
                                               double* stDp, uint64_t* stM, int w) {
    __shared__ double ring[128][64];
    rscanA_body(cur, prev, s1w, stY1, stY2, stR1, stR2, stDp, stM,
                w, threadIdx.x, blockIdx.x, ring);
}
__global__ __launch_bounds__(64) void k_rscan0(const double* __restrict__ cur,
                                               uint64_t* __restrict__ s1w,
                                               double* stY1, double* stY2,
                                               double* stR1, double* stR2,
                                               double* stDp, uint64_t* stM,
                                               const double* __restrict__ e,
                                               const int* __restrict__ perm,
                                               uint64_t* __restrict__ s1bw) {
    __shared__ double ring[128][64];
    __shared__ int pl[156];
    int b = blockIdx.x, lane = threadIdx.x;
    if (b < 512) {
        rscanA_body(cur, cur, s1w, stY1, stY2, stR1, stR2, stDp, stM,
                    0, lane, b, ring);
    } else {
        for (int i = lane; i < 156; i += 64) pl[i] = perm[i];
        __syncthreads();
        rscanB_body(e, pl, s1bw, lane, b - 512, ring);
    }
}

// ---------------------------------------------------------------------------
// DENSE2 (merged A+B): a2[t][1280], a2b[j][1280], col = n*20+o. (unchanged)
__global__ __launch_bounds__(256) void k_dense2m(const uint64_t* __restrict__ s1w,
                                                 const uint64_t* __restrict__ s1bw,
                                                 const float* __restrict__ w_fc2,
                                                 const float* __restrict__ w_loc2,
                                                 double* __restrict__ a2,
                                                 double* __restrict__ a2b) {
    __shared__ float wt[512 * 20];
    int b = blockIdx.x, tid = threadIdx.x;
    int isA = (b < 125);
    const float* w = isA ? w_fc2 : w_loc2;
    const uint64_t* sw = isA ? s1w : s1bw;
    double* a = isA ? a2 : a2b;
    int T = isA ? 500 : 156;
    int gid = (isA ? b : (b - 125)) * 256 + tid;
    for (int e = tid; e < 512 * 20; e += 256) { int o = e / 512, hh = e % 512; wt[hh * 20 + o] = w[e]; }
    __syncthreads();
    if (gid >= 64 * T) return;
    int n = gid / T, t = gid - n * T;
    const uint64_t* r = sw + ((size_t)n * T + t) * 8;
    uint64_t wbuf[8];
#pragma unroll
    for (int wd = 0; wd < 8; ++wd) wbuf[wd] = r[wd];
    double acc[20];
#pragma unroll
    for (int o = 0; o < 20; ++o) acc[o] = 0.0;
#pragma unroll
    for (int wd = 0; wd < 8; ++wd) {
        uint64_t mw = wbuf[wd];
        while (mw) {
            int bb = __builtin_ctzll(mw);
            const float* wp = wt + (wd * 64 + bb) * 20;
#pragma unroll
            for (int o = 0; o < 20; ++o) acc[o] += (double)wp[o];
            mw &= mw - 1;
        }
    }
#pragma unroll
    for (int o = 0; o < 20; ++o) a[(size_t)t * 1280 + n * 20 + o] = acc[o];
}

// ---------------------------------------------------------------------------
// OUT (k_out3): 24-step chunks (unchanged, R13-proven).
template<int NFULL, int TAIL>
__device__ __forceinline__ void ring_scan(const double* __restrict__ a, int row,
                                          double (*ring)[64],
                                          uint32_t (*bits)[64], int lane) {
    RC rc = make_rc();
    double y1 = 0.0, y2 = 0.0, R1 = 0.0, R2 = 0.0, dp = 0.0; uint64_t mask = 0;
    double cur[24], nxt[24];
#pragma unroll
    for (int i = 0; i < 24; ++i) cur[i] = a[(size_t)i * 1280 + row];
    for (int ch = 0; ch < NFULL; ++ch) {
        int t0 = ch * 24;
        if (ch + 1 < NFULL) {
#pragma unroll
            for (int i = 0; i < 24; ++i) nxt[i] = a[(size_t)(t0 + 24 + i) * 1280 + row];
        } else if (TAIL > 0) {
#pragma unroll
            for (int i = 0; i < 24; ++i)
                nxt[i] = (i < TAIL) ? a[(size_t)(t0 + 24 + i) * 1280 + row] : 0.0;
        }
#pragma unroll
        for (int i = 0; i < 24; ++i) ring[(t0 + i) & 127][lane] = cur[i];
        double tap[25];
#pragma unroll
        for (int i = 0; i < 25; ++i) {
            int l = t0 + i - 101;
            tap[i] = (l >= 0) ? ring[l & 127][lane] : 0.0;
        }
        uint32_t sp = 0;
#pragma unroll
        for (int i = 0; i < 24; ++i) {
            int s = rstep(rc, (i == 0) ? dp : cur[i - 1], tap[i + 1], tap[i],
                          y1, y2, R1, R2, mask);
            sp |= (uint32_t)s << i;
        }
        dp = cur[23];
        bits[ch][lane] = sp;
#pragma unroll
        for (int i = 0; i < 24; ++i) cur[i] = nxt[i];
    }
    if (TAIL > 0) {
        int t0 = NFULL * 24;
#pragma unroll
        for (int i = 0; i < 24; ++i) if (i < TAIL) ring[(t0 + i) & 127][lane] = cur[i];
        double tap[25];
#pragma unroll
        for (int i = 0; i < 25; ++i) {
            if (i > TAIL) break;
            int l = t0 + i - 101;
            tap[i] = (l >= 0) ? ring[l & 127][lane] : 0.0;
        }
        uint32_t sp = 0;
#pragma unroll
        for (int i = 0; i < 24; ++i) {
            if (i >= TAIL) break;
            int s = rstep(rc, (i == 0) ? dp : cur[i - 1], tap[i + 1], tap[i],
                          y1, y2, R1, R2, mask);
            sp |= (uint32_t)s << i;
        }
        bits[NFULL][lane] = sp;
    }
}

template<int T>
__device__ __forceinline__ void expand_bits(uint32_t (*bits)[64],
                                            float* __restrict__ out,
                                            int row0, int coff, int lane) {
    for (int r = 0; r < 64; ++r) {
        float* orow = out + (size_t)(row0 + r) * 656 + coff;
        for (int c0 = 0; c0 < T; c0 += 64) {
            int c = c0 + lane;
            if (c < T) orow[c] = (float)((bits[c / 24][r] >> (c % 24)) & 1);
        }
    }
}

__global__ __launch_bounds__(64) void k_out3(const double* __restrict__ a2,
                                             const double* __restrict__ a2b,
                                             float* __restrict__ out) {
    __shared__ double ring[128][64];
    __shared__ uint32_t bits[21][64];
    int b = blockIdx.x, lane = threadIdx.x;
    if (b < 20) {
        int row0 = b * 64;
        ring_scan<20, 20>(a2, row0 + lane, ring, bits, lane);   // 500 = 20*24+20
        expand_bits<500>(bits, out, row0, 0, lane);
    } else {
        int row0 = (b - 20) * 64;
        ring_scan<6, 12>(a2b, row0 + lane, ring, bits, lane);   // 156 = 6*24+12
        expand_bits<156>(bits, out, row0, 500, lane);
    }
}

// ---------------------------------------------------------------------------
extern "C" void kernel_launch(void* const* d_in, const int* in_sizes, int n_in,
                              void* d_out, int out_size, void* d_ws, size_t ws_size,
                              hipStream_t stream) {
    const float* x      = (const float*)d_in[0];
    const float* w_fc1  = (const float*)d_in[1];
    const float* w_fc2  = (const float*)d_in[2];
    const float* w_loc1 = (const float*)d_in[3];
    const float* w_loc2 = (const float*)d_in[4];
    const int*   perm   = (const int*)d_in[5];
    float* out = (float*)d_out;
    char* ws = (char*)d_ws;
    (void)in_sizes; (void)n_in; (void)out_size;

    const size_t NEED_MAIN = 184889344;
    if (ws_size >= NEED_MAIN) {
        // ---- single-window layout: d1 full (131 MB), no checkpoints ----
        double*   d1   = (double*)(ws + 0);             // 131,072,000 B [500][32768]
        double*   e    = (double*)(ws + 131072000);     //  40,894,464 B
        double*   a2   = (double*)(ws + 171966464);     //   5,120,000 B
        double*   a2b  = (double*)(ws + 177086464);     //   1,597,440 B
        uint64_t* s1w  = (uint64_t*)(ws + 178683904);   //   2,560,000 B
        uint64_t* s1bw = (uint64_t*)(ws + 181243904);   //     638,976 B
        uint64_t* xb   = (uint64_t*)(ws + 181882880);   //   1,024,000 B
        uint64_t* xbT  = (uint64_t*)(ws + 182906880);   //     638,976 B
        float*    w1t  = (float*)(ws + 183545856);      //     319,488 B
        float*    wl1t = (float*)(ws + 183865344);      //   1,024,000 B

        k_prep<<<600, 256, 0, stream>>>(x, w_fc1, w_loc1, xb, xbT, w1t, wl1t);
        k_sdense_full<<<41984, 128, 0, stream>>>(xb, w1t, d1, xbT, wl1t, e);
        k_rscan_full<<<1024, 64, 0, stream>>>(d1, s1w, e, perm, s1bw);
        k_dense2m<<<164, 256, 0, stream>>>(s1w, s1bw, w_fc2, w_loc2, a2, a2b);
        k_out3<<<40, 64, 0, stream>>>(a2, a2b, out);
        return;
    }

    // ---- fallback: R16-proven window structure (quad-h bodies) ----
    double*   d1b0 = (double*)(ws + 0);             // 32,768,000 B
    double*   d1b1 = (double*)(ws + 32768000);      // 32,768,000 B
    double*   a2   = (double*)(ws + 40894464);      //  5,120,000 B (overlays d1b1; dead by then)
    double*   a2b  = (double*)(ws + 46014464);      //  1,597,440 B
    double*   e    = (double*)(ws + 65536000);      // 40,894,464 B
    uint64_t* s1w  = (uint64_t*)(ws + 106430464);   //  2,560,000 B
    uint64_t* s1bw = (uint64_t*)(ws + 108990464);   //    638,976 B
    uint64_t* xb   = (uint64_t*)(ws + 109629440);   //  1,024,000 B
    uint64_t* xbT  = (uint64_t*)(ws + 110653440);   //    638,976 B
    float*    w1t  = (float*)(ws + 111292416);      //    319,488 B
    float*    wl1t = (float*)(ws + 111611904);      //  1,024,000 B
    double*   stY1 = (double*)(ws + 112635904);
    double*   stY2 = (double*)(ws + 112898048);
    double*   stR1 = (double*)(ws + 113160192);
    double*   stR2 = (double*)(ws + 113422336);
    double*   stDp = (double*)(ws + 113684480);
    uint64_t* stM  = (uint64_t*)(ws + 113946624);

    k_prep<<<600, 256, 0, stream>>>(x, w_fc1, w_loc1, xb, xbT, w1t, wl1t);
    k_sdense0_fb<<<17984, 128, 0, stream>>>(xb, w1t, d1b0, xbT, wl1t, e);
    k_rscan0<<<1024, 64, 0, stream>>>(d1b0, s1w, stY1, stY2, stR1, stR2, stDp, stM, e, perm, s1bw);
    dim3 ga(125, 64);
    for (int w = 1; w < 4; ++w) {
        double* cur  = (w & 1) ? d1b1 : d1b0;
        double* prev = (w & 1) ? d1b0 : d1b1;
        k_sdenseA_fb<<<ga, 128, 0, stream>>>(xb, w1t, cur, w);
        k_rscanA<<<512, 64, 0, stream>>>(cur, prev, s1w, stY1, stY2, stR1, stR2, stDp, stM, w);
    }
    k_dense2m<<<164, 256, 0, stream>>>(s1w, s1bw, w_fc2, w_loc2, a2, a2b);
    k_out3<<<40, 64, 0, stream>>>(a2, a2b, out);
}